// Round 1
// baseline (3291.937 us; speedup 1.0000x reference)
//
#include <hip/hip_runtime.h>
#include <hip/hip_bf16.h>
#include <math.h>

#define B_ 256
#define T_ 256
#define HLS 128

__device__ __forceinline__ float leakyf(float v) { return v > 0.f ? v : 0.01f * v; }
__device__ __forceinline__ float sigf(float v)   { return 1.f / (1.f + expf(-v)); }

// ---------------------------------------------------------------- conv1: [B,T,8] -> [B,T,32]
__global__ __launch_bounds__(256) void conv1_kernel(
    const float* __restrict__ x, const float* __restrict__ W,
    const float* __restrict__ bias, float* __restrict__ out)
{
    int tid  = threadIdx.x;
    int co   = tid & 31;
    int tsub = tid >> 5;                 // 0..7
    int b    = blockIdx.x >> 5;          // 32 t-tiles per batch
    int t    = ((blockIdx.x & 31) << 3) + tsub;
    float acc = bias[co];
    #pragma unroll
    for (int k = 0; k < 5; ++k) {
        int tt = t + k - 2;
        if (tt < 0 || tt >= T_) continue;
        const float* xr = x + ((size_t)b * T_ + tt) * 8;
        #pragma unroll
        for (int ci = 0; ci < 8; ++ci)
            acc += xr[ci] * W[(k * 8 + ci) * 32 + co];
    }
    out[((size_t)b * T_ + t) * 32 + co] = leakyf(acc);
}

// ---------------------------------------------------------------- conv2: [B,T,32] -> [B,T,512]
__global__ __launch_bounds__(256) void conv2_kernel(
    const float* __restrict__ in, const float* __restrict__ W,
    const float* __restrict__ bias, float* __restrict__ out)
{
    __shared__ float lin[12][32];        // rows t0-2 .. t0+9
    int tid = threadIdx.x;
    int b   = blockIdx.x >> 5;           // T/8 = 32 tiles per batch
    int t0  = (blockIdx.x & 31) << 3;

    for (int idx = tid; idx < 12 * 32; idx += 256) {
        int row = idx >> 5, ci = idx & 31;
        int t = t0 - 2 + row;
        lin[row][ci] = (t >= 0 && t < T_) ? in[((size_t)b * T_ + t) * 32 + ci] : 0.f;
    }
    __syncthreads();

    float acc0[8], acc1[8];
    float bb0 = bias[tid], bb1 = bias[tid + 256];
    #pragma unroll
    for (int j = 0; j < 8; ++j) { acc0[j] = bb0; acc1[j] = bb1; }

    for (int k = 0; k < 5; ++k)
        for (int ci = 0; ci < 32; ++ci) {
            float w0 = W[((k * 32) + ci) * 512 + tid];
            float w1 = W[((k * 32) + ci) * 512 + tid + 256];
            #pragma unroll
            for (int tt = 0; tt < 8; ++tt) {
                float v = lin[tt + k][ci];
                acc0[tt] += v * w0;
                acc1[tt] += v * w1;
            }
        }

    for (int tt = 0; tt < 8; ++tt) {
        size_t o = ((size_t)b * T_ + t0 + tt) * 512;
        out[o + tid]       = leakyf(acc0[tt]);
        out[o + tid + 256] = leakyf(acc1[tt]);
    }
}

// ---------------------------------------------------------------- conv3: [B,T,512] -> [B,T,128]
__global__ __launch_bounds__(256) void conv3_kernel(
    const float* __restrict__ in, const float* __restrict__ W,
    const float* __restrict__ bias, float* __restrict__ out)
{
    __shared__ float lin[20 * 512];      // rows t0-2 .. t0+17 (40 KB)
    int tid = threadIdx.x;
    int b   = blockIdx.x >> 4;           // T/16 = 16 tiles per batch
    int t0  = (blockIdx.x & 15) << 4;

    for (int idx = tid; idx < 20 * 512; idx += 256) {
        int row = idx >> 9, ci = idx & 511;
        int t = t0 - 2 + row;
        lin[idx] = (t >= 0 && t < T_) ? in[((size_t)b * T_ + t) * 512 + ci] : 0.f;
    }
    __syncthreads();

    int co = tid & 127, half = tid >> 7; // half selects t-subgroup
    float acc[8];
    float bb = bias[co];
    #pragma unroll
    for (int j = 0; j < 8; ++j) acc[j] = bb;

    for (int k = 0; k < 5; ++k)
        for (int ci4 = 0; ci4 < 128; ++ci4) {
            int ci = ci4 << 2;
            float w0 = W[((k << 9) + ci + 0) * 128 + co];
            float w1 = W[((k << 9) + ci + 1) * 128 + co];
            float w2 = W[((k << 9) + ci + 2) * 128 + co];
            float w3 = W[((k << 9) + ci + 3) * 128 + co];
            #pragma unroll
            for (int j = 0; j < 8; ++j) {
                const float4 v = *(const float4*)&lin[((half << 3) + j + k) * 512 + ci];
                acc[j] += v.x * w0 + v.y * w1 + v.z * w2 + v.w * w3;
            }
        }

    #pragma unroll
    for (int j = 0; j < 8; ++j) {
        int t = t0 + (half << 3) + j;
        out[((size_t)b * T_ + t) * 128 + co] = leakyf(acc[j]);
    }
}

// ---------------------------------------------------------------- tiled fp32 GEMM (+bias), optional split-K via blockIdx.z
// C[z][m,n] = sum_{k in [z*klen, (z+1)*klen)} A[m,k]*B[k,n]  (+ bias[n] if bias)
__global__ __launch_bounds__(256) void gemm_kernel(
    const float* __restrict__ A, const float* __restrict__ Bm,
    const float* __restrict__ bias, float* __restrict__ C,
    int M, int N, int K, int klen)
{
    __shared__ float As[16][68];
    __shared__ float Bs[16][68];
    const int tid = threadIdx.x;
    const int mt  = blockIdx.x * 64;
    const int nt  = blockIdx.y * 64;
    const int k0  = blockIdx.z * klen;
    float* Cc = C + (size_t)blockIdx.z * M * N;

    const int tx = tid & 15, ty = tid >> 4;
    const int am = tid >> 2, ak4 = (tid & 3) << 2;   // A tile load mapping
    const int bk = tid >> 4, bn4 = (tid & 15) << 2;  // B tile load mapping

    float acc[4][4] = {};
    for (int kk = 0; kk < klen; kk += 16) {
        const int kb = k0 + kk;
        const float4 av = *(const float4*)&A[(size_t)(mt + am) * K + kb + ak4];
        const float4 bv = *(const float4*)&Bm[(size_t)(kb + bk) * N + nt + bn4];
        __syncthreads();
        As[ak4 + 0][am] = av.x; As[ak4 + 1][am] = av.y;
        As[ak4 + 2][am] = av.z; As[ak4 + 3][am] = av.w;
        *(float4*)&Bs[bk][bn4] = bv;
        __syncthreads();
        #pragma unroll
        for (int k = 0; k < 16; ++k) {
            const float4 a4 = *(const float4*)&As[k][ty << 2];
            const float4 b4 = *(const float4*)&Bs[k][tx << 2];
            const float avr[4] = {a4.x, a4.y, a4.z, a4.w};
            const float bvr[4] = {b4.x, b4.y, b4.z, b4.w};
            #pragma unroll
            for (int i = 0; i < 4; ++i)
                #pragma unroll
                for (int j = 0; j < 4; ++j)
                    acc[i][j] += avr[i] * bvr[j];
        }
    }
    #pragma unroll
    for (int i = 0; i < 4; ++i) {
        int m = mt + (ty << 2) + i;
        #pragma unroll
        for (int j = 0; j < 4; ++j) {
            int n = nt + (tx << 2) + j;
            float v = acc[i][j];
            if (bias) v += bias[n];
            Cc[(size_t)m * N + n] = v;
        }
    }
}

// ---------------------------------------------------------------- LSTM layer (sequential over T)
// X = x@Wx + b precomputed: [B,T,512]. 2 batch rows per block, 512 threads.
__global__ __launch_bounds__(512) void lstm_kernel(
    const float* __restrict__ X, const float* __restrict__ Wh,
    const float* __restrict__ cin, const float* __restrict__ hin,
    float* __restrict__ out, float* __restrict__ cfin, float* __restrict__ hfin,
    int initZero)
{
    __shared__ float lh[2][128];
    __shared__ float lz[2][512];
    const int tid = threadIdx.x;      // 0..511 ; j = tid
    const int b0  = blockIdx.x * 2;
    const int gb  = (tid >> 7) & 1;   // gate-phase batch (tid<256)
    const int gm  = tid & 127;        // gate-phase hidden index

    float creg = 0.f;
    if (tid < 256) {
        if (initZero) {
            creg = 0.f;
            lh[gb][gm] = 0.f;
        } else {
            creg = cin[(size_t)(b0 + gb) * 128 + gm];
            lh[gb][gm] = hin[(size_t)(b0 + gb) * 128 + gm];
        }
    }
    __syncthreads();

    for (int t = 0; t < T_; ++t) {
        float acc0 = X[((size_t)(b0 + 0) * T_ + t) * 512 + tid];
        float acc1 = X[((size_t)(b0 + 1) * T_ + t) * 512 + tid];
        #pragma unroll 8
        for (int k = 0; k < 128; ++k) {
            float w = Wh[k * 512 + tid];
            acc0 += lh[0][k] * w;
            acc1 += lh[1][k] * w;
        }
        __syncthreads();              // lh reads done before gate phase rewrites it
        lz[0][tid] = acc0;
        lz[1][tid] = acc1;
        __syncthreads();
        if (tid < 256) {
            float zi = lz[gb][gm];
            float zf = lz[gb][gm + 128];
            float zg = lz[gb][gm + 256];
            float zo = lz[gb][gm + 384];
            float ig = sigf(zi), fg = sigf(zf), gg = tanhf(zg), og = sigf(zo);
            creg = fg * creg + ig * gg;
            float h = og * tanhf(creg);
            lh[gb][gm] = h;
            out[((size_t)(b0 + gb) * T_ + t) * 128 + gm] = h;
        }
        __syncthreads();
    }
    if (tid < 256) {
        cfin[(size_t)(b0 + gb) * 128 + gm] = creg;
        hfin[(size_t)(b0 + gb) * 128 + gm] = lh[gb][gm];
    }
}

// ---------------------------------------------------------------- split-K reduce + bias for dense layer
__global__ __launch_bounds__(256) void reduce_kernel(
    const float* __restrict__ part, const float* __restrict__ bias,
    float* __restrict__ d)
{
    int i = blockIdx.x * 256 + threadIdx.x;   // 0..131071
    float s = bias[i & 511];
    #pragma unroll
    for (int p = 0; p < 16; ++p) s += part[(size_t)p * 131072 + i];
    d[i] = s;
}

// ---------------------------------------------------------------- BatchNorm (batch stats over 256 rows) + leaky
__global__ __launch_bounds__(256) void bn_kernel(
    float* __restrict__ d, const float* __restrict__ scale, const float* __restrict__ bias)
{
    int j = blockIdx.x * 256 + threadIdx.x;   // column 0..511
    float s = 0.f, s2 = 0.f;
    for (int m = 0; m < 256; ++m) {
        float v = d[(size_t)m * 512 + j];
        s += v; s2 += v * v;
    }
    float mean = s * (1.f / 256.f);
    float var  = s2 * (1.f / 256.f) - mean * mean;
    float inv  = rsqrtf(var + 1e-5f);
    float sc = scale[j] * inv;
    float bi = bias[j] - mean * sc;
    for (int m = 0; m < 256; ++m) {
        float v = d[(size_t)m * 512 + j] * sc + bi;
        d[(size_t)m * 512 + j] = leakyf(v);
    }
}

// ---------------------------------------------------------------- head: d[256,512] @ Wd2[512,10] + bd2 -> softmax
__global__ __launch_bounds__(64) void head_kernel(
    const float* __restrict__ d, const float* __restrict__ Wd2,
    const float* __restrict__ bd2, float* __restrict__ out)
{
    int r = blockIdx.x, l = threadIdx.x;
    float acc[10] = {};
    for (int k = l; k < 512; k += 64) {
        float v = d[(size_t)r * 512 + k];
        #pragma unroll
        for (int n = 0; n < 10; ++n) acc[n] += v * Wd2[k * 10 + n];
    }
    #pragma unroll
    for (int n = 0; n < 10; ++n)
        for (int off = 32; off; off >>= 1) acc[n] += __shfl_down(acc[n], off);
    if (l == 0) {
        float mx = -1e30f;
        #pragma unroll
        for (int n = 0; n < 10; ++n) { acc[n] += bd2[n]; mx = fmaxf(mx, acc[n]); }
        float s = 0.f;
        #pragma unroll
        for (int n = 0; n < 10; ++n) { acc[n] = expf(acc[n] - mx); s += acc[n]; }
        float invs = 1.f / s;
        #pragma unroll
        for (int n = 0; n < 10; ++n) out[(size_t)r * 10 + n] = acc[n] * invs;
    }
}

// ----------------------------------------------------------------
extern "C" void kernel_launch(void* const* d_in, const int* in_sizes, int n_in,
                              void* d_out, int out_size, void* d_ws, size_t ws_size,
                              hipStream_t stream)
{
    const float* x   = (const float*)d_in[0];
    const float* W1  = (const float*)d_in[1];
    const float* bc1 = (const float*)d_in[2];
    const float* W2  = (const float*)d_in[3];
    const float* bc2 = (const float*)d_in[4];
    const float* W3  = (const float*)d_in[5];
    const float* bc3 = (const float*)d_in[6];
    const float* Wx1 = (const float*)d_in[7];
    const float* Wh1 = (const float*)d_in[8];
    const float* b1  = (const float*)d_in[9];
    const float* Wx2 = (const float*)d_in[10];
    const float* Wh2 = (const float*)d_in[11];
    const float* b2  = (const float*)d_in[12];
    const float* Wd1 = (const float*)d_in[13];
    const float* bd1 = (const float*)d_in[14];
    const float* bns = (const float*)d_in[15];
    const float* bnb = (const float*)d_in[16];
    const float* Wd2 = (const float*)d_in[17];
    const float* bd2 = (const float*)d_in[18];
    float* outp = (float*)d_out;

    const size_t BT = (size_t)B_ * T_;
    float* ws   = (float*)d_ws;
    float* bufA = ws;                    // BT*512  : a2 -> X1 -> X2
    float* bufC = bufA + BT * 512;       // BT*128  : a3 -> out2
    float* bufD = bufC + BT * 128;       // BT*128  : out1
    float* bufE = bufD + BT * 128;       // BT*32   : a1 -> dense split-K partials (16*256*512 == BT*32)
    float* bufd = bufE + BT * 32;        // 256*512 : dense output
    float* cf   = bufd + (size_t)256 * 512;
    float* hf   = cf + (size_t)B_ * HLS;
    float* bufP = bufE;                  // reuse: a1 dead after conv2

    // convs
    conv1_kernel<<<dim3(B_ * T_ / 8), dim3(256), 0, stream>>>(x, W1, bc1, bufE);
    conv2_kernel<<<dim3(B_ * T_ / 8), dim3(256), 0, stream>>>(bufE, W2, bc2, bufA);
    conv3_kernel<<<dim3(B_ * T_ / 16), dim3(256), 0, stream>>>(bufA, W3, bc3, bufC);

    // X1 = a3 @ Wx1 + b1  (a2 in bufA dead)
    gemm_kernel<<<dim3(1024, 8, 1), dim3(256), 0, stream>>>(bufC, Wx1, b1, bufA, 65536, 512, 128, 128);
    // LSTM layer 1 (zero init carry), out1 -> bufD, final carry -> cf/hf
    lstm_kernel<<<dim3(128), dim3(512), 0, stream>>>(bufA, Wh1, nullptr, nullptr, bufD, cf, hf, 1);
    // X2 = out1 @ Wx2 + b2 (X1 dead)
    gemm_kernel<<<dim3(1024, 8, 1), dim3(256), 0, stream>>>(bufD, Wx2, b2, bufA, 65536, 512, 128, 128);
    // LSTM layer 2 (init carry = layer-1 final), out2 -> bufC (a3 dead)
    lstm_kernel<<<dim3(128), dim3(512), 0, stream>>>(bufA, Wh2, cf, hf, bufC, cf, hf, 0);

    // dense: [256, 32768] @ [32768, 512], split-K 16 x 2048
    gemm_kernel<<<dim3(4, 8, 16), dim3(256), 0, stream>>>(bufC, Wd1, nullptr, bufP, 256, 512, 32768, 2048);
    reduce_kernel<<<dim3(512), dim3(256), 0, stream>>>(bufP, bd1, bufd);

    // batchnorm + leaky, then head + softmax
    bn_kernel<<<dim3(2), dim3(256), 0, stream>>>(bufd, bns, bnb);
    head_kernel<<<dim3(256), dim3(64), 0, stream>>>(bufd, Wd2, bd2, outp);
}

// Round 2
// 1502.436 us; speedup vs baseline: 2.1911x; 2.1911x over previous
//
#include <hip/hip_runtime.h>
#include <hip/hip_bf16.h>
#include <math.h>

#define B_ 256
#define T_ 256
#define HLS 128

typedef __bf16 bf16x8 __attribute__((ext_vector_type(8)));
typedef float f32x4 __attribute__((ext_vector_type(4)));
typedef unsigned int u32x4 __attribute__((ext_vector_type(4)));

__device__ __forceinline__ float leakyf(float v) { return v > 0.f ? v : 0.01f * v; }
__device__ __forceinline__ float sigf(float v)   { return 1.f / (1.f + expf(-v)); }

// ---------------------------------------------------------------- conv1: [B,T,8] -> [B,T,32] fp32
__global__ __launch_bounds__(256) void conv1_kernel(
    const float* __restrict__ x, const float* __restrict__ W,
    const float* __restrict__ bias, float* __restrict__ out)
{
    int tid  = threadIdx.x;
    int co   = tid & 31;
    int tsub = tid >> 5;                 // 0..7
    int b    = blockIdx.x >> 5;
    int t    = ((blockIdx.x & 31) << 3) + tsub;
    float acc = bias[co];
    #pragma unroll
    for (int k = 0; k < 5; ++k) {
        int tt = t + k - 2;
        if (tt < 0 || tt >= T_) continue;
        const float* xr = x + ((size_t)b * T_ + tt) * 8;
        #pragma unroll
        for (int ci = 0; ci < 8; ++ci)
            acc += xr[ci] * W[(k * 8 + ci) * 32 + co];
    }
    out[((size_t)b * T_ + t) * 32 + co] = leakyf(acc);
}

// ---------------------------------------------------------------- conv2: [B,T,32] -> [B,T,512] bf16
__global__ __launch_bounds__(256) void conv2_kernel(
    const float* __restrict__ in, const float* __restrict__ W,
    const float* __restrict__ bias, __hip_bfloat16* __restrict__ out)
{
    __shared__ float lin[20][32];        // rows t0-2 .. t0+17
    int tid = threadIdx.x;
    int b   = blockIdx.x >> 4;           // 16 t-tiles per batch
    int t0  = (blockIdx.x & 15) << 4;

    for (int idx = tid; idx < 20 * 32; idx += 256) {
        int row = idx >> 5, ci = idx & 31;
        int t = t0 - 2 + row;
        lin[row][ci] = (t >= 0 && t < T_) ? in[((size_t)b * T_ + t) * 32 + ci] : 0.f;
    }
    __syncthreads();

    float acc0[16], acc1[16];
    float bb0 = bias[tid], bb1 = bias[tid + 256];
    #pragma unroll
    for (int j = 0; j < 16; ++j) { acc0[j] = bb0; acc1[j] = bb1; }

    for (int k = 0; k < 5; ++k)
        for (int ci = 0; ci < 32; ++ci) {
            float w0 = W[((k * 32) + ci) * 512 + tid];
            float w1 = W[((k * 32) + ci) * 512 + tid + 256];
            #pragma unroll
            for (int tt = 0; tt < 16; ++tt) {
                float v = lin[tt + k][ci];
                acc0[tt] += v * w0;
                acc1[tt] += v * w1;
            }
        }

    for (int tt = 0; tt < 16; ++tt) {
        size_t o = ((size_t)b * T_ + t0 + tt) * 512;
        out[o + tid]       = __float2bfloat16(leakyf(acc0[tt]));
        out[o + tid + 256] = __float2bfloat16(leakyf(acc1[tt]));
    }
}

// ---------------------------------------------------------------- prep: Wh[128,512] -> WhT[512,128] fp32
__global__ __launch_bounds__(256) void prep_wht(const float* __restrict__ Wh, float* __restrict__ WhT)
{
    int idx = blockIdx.x * 256 + threadIdx.x;   // 0..65535
    int j = idx & 511, k = idx >> 9;
    WhT[j * 128 + k] = Wh[idx];
}

// ---------------------------------------------------------------- prep: W3[5,512,128] fp32 -> W3T[5,128,512] bf16
__global__ __launch_bounds__(256) void prep_w3t(const float* __restrict__ W3, __hip_bfloat16* __restrict__ W3T)
{
    int idx = blockIdx.x * 256 + threadIdx.x;   // 0..327679
    int co = idx & 127, rest = idx >> 7;
    int ci = rest & 511, k = rest >> 9;
    W3T[((size_t)(k * 128 + co)) * 512 + ci] = __float2bfloat16(W3[idx]);
}

// ---------------------------------------------------------------- conv3 as bf16 MFMA implicit GEMM
// out[b,t,co] = leaky(sum_k sum_ci a2[b,t+k-2,ci]*W3[k,ci,co] + bias), M-tile 64, N 128
__global__ __launch_bounds__(256) void conv3_mfma(
    const __hip_bfloat16* __restrict__ a2,   // [B,T,512] bf16
    const __hip_bfloat16* __restrict__ W3T,  // [5,128,512] bf16
    const float* __restrict__ bias, float* __restrict__ out)
{
    const int tid = threadIdx.x, lane = tid & 63, wave = tid >> 6;
    const int wm = wave & 1, wn = wave >> 1;     // 2x2 wave grid
    const int b  = blockIdx.x >> 2;
    const int t0 = (blockIdx.x & 3) << 6;
    const int lr = lane & 15, lg = lane >> 4;

    f32x4 acc[2][4];
    #pragma unroll
    for (int i = 0; i < 2; ++i)
        #pragma unroll
        for (int j = 0; j < 4; ++j) acc[i][j] = (f32x4){0.f, 0.f, 0.f, 0.f};

    const __hip_bfloat16* a2b = a2 + (size_t)b * T_ * 512;

    for (int k = 0; k < 5; ++k) {
        const int r0 = t0 + wm * 32 + lr + k - 2;
        const __hip_bfloat16* wbase = W3T + ((size_t)(k * 128 + wn * 64 + lr)) * 512;
        for (int ci0 = 0; ci0 < 512; ci0 += 32) {
            const int ci = ci0 + lg * 8;
            bf16x8 af[2];
            #pragma unroll
            for (int fm = 0; fm < 2; ++fm) {
                int trow = r0 + fm * 16;
                u32x4 au = {0u, 0u, 0u, 0u};
                if (trow >= 0 && trow < T_)
                    au = *(const u32x4*)(a2b + (size_t)trow * 512 + ci);
                af[fm] = __builtin_bit_cast(bf16x8, au);
            }
            #pragma unroll
            for (int fn = 0; fn < 4; ++fn) {
                bf16x8 bf = *(const bf16x8*)(wbase + (size_t)fn * 16 * 512 + ci);
                acc[0][fn] = __builtin_amdgcn_mfma_f32_16x16x32_bf16(af[0], bf, acc[0][fn], 0, 0, 0);
                acc[1][fn] = __builtin_amdgcn_mfma_f32_16x16x32_bf16(af[1], bf, acc[1][fn], 0, 0, 0);
            }
        }
    }
    #pragma unroll
    for (int fm = 0; fm < 2; ++fm)
        #pragma unroll
        for (int fn = 0; fn < 4; ++fn) {
            int co = wn * 64 + fn * 16 + lr;
            float bb = bias[co];
            #pragma unroll
            for (int r = 0; r < 4; ++r) {
                int t = t0 + wm * 32 + fm * 16 + lg * 4 + r;
                out[((size_t)b * T_ + t) * 128 + co] = leakyf(acc[fm][fn][r] + bb);
            }
        }
}

// ---------------------------------------------------------------- tiled fp32 GEMM (+bias), split-K via blockIdx.z
__global__ __launch_bounds__(256) void gemm_kernel(
    const float* __restrict__ A, const float* __restrict__ Bm,
    const float* __restrict__ bias, float* __restrict__ C,
    int M, int N, int K, int klen)
{
    __shared__ float As[16][68];
    __shared__ float Bs[16][68];
    const int tid = threadIdx.x;
    const int mt  = blockIdx.x * 64;
    const int nt  = blockIdx.y * 64;
    const int k0  = blockIdx.z * klen;
    float* Cc = C + (size_t)blockIdx.z * M * N;

    const int tx = tid & 15, ty = tid >> 4;
    const int am = tid >> 2, ak4 = (tid & 3) << 2;
    const int bk = tid >> 4, bn4 = (tid & 15) << 2;

    float acc[4][4] = {};
    for (int kk = 0; kk < klen; kk += 16) {
        const int kb = k0 + kk;
        const float4 av = *(const float4*)&A[(size_t)(mt + am) * K + kb + ak4];
        const float4 bv = *(const float4*)&Bm[(size_t)(kb + bk) * N + nt + bn4];
        __syncthreads();
        As[ak4 + 0][am] = av.x; As[ak4 + 1][am] = av.y;
        As[ak4 + 2][am] = av.z; As[ak4 + 3][am] = av.w;
        *(float4*)&Bs[bk][bn4] = bv;
        __syncthreads();
        #pragma unroll
        for (int k = 0; k < 16; ++k) {
            const float4 a4 = *(const float4*)&As[k][ty << 2];
            const float4 b4 = *(const float4*)&Bs[k][tx << 2];
            const float avr[4] = {a4.x, a4.y, a4.z, a4.w};
            const float bvr[4] = {b4.x, b4.y, b4.z, b4.w};
            #pragma unroll
            for (int i = 0; i < 4; ++i)
                #pragma unroll
                for (int j = 0; j < 4; ++j)
                    acc[i][j] += avr[i] * bvr[j];
        }
    }
    #pragma unroll
    for (int i = 0; i < 4; ++i) {
        int m = mt + (ty << 2) + i;
        #pragma unroll
        for (int j = 0; j < 4; ++j) {
            int n = nt + (tx << 2) + j;
            float v = acc[i][j];
            if (bias) v += bias[n];
            Cc[(size_t)m * N + n] = v;
        }
    }
}

// ---------------------------------------------------------------- LSTM layer, 1 batch row / block, Wh in registers
__global__ __launch_bounds__(1024, 4) void lstm2_kernel(
    const float* __restrict__ X, const float* __restrict__ WhT,
    const float* __restrict__ cin, const float* __restrict__ hin,
    float* __restrict__ out, float* __restrict__ cf, float* __restrict__ hf,
    int initZero)
{
    __shared__ __align__(16) float lh[128];
    __shared__ float lz[1024];
    const int tid  = threadIdx.x;
    const int j    = tid & 511;     // gate column
    const int half = tid >> 9;      // K split
    const int b    = blockIdx.x;

    float4 w[16];
    {
        const float4* wp = (const float4*)(WhT + (size_t)j * 128 + half * 64);
        #pragma unroll
        for (int i = 0; i < 16; ++i) w[i] = wp[i];
    }
    float creg = 0.f;
    if (tid < 128) {
        if (initZero) { creg = 0.f; lh[tid] = 0.f; }
        else { creg = cin[(size_t)b * 128 + tid]; lh[tid] = hin[(size_t)b * 128 + tid]; }
    }
    __syncthreads();

    const float* Xr = X + (size_t)b * T_ * 512;
    float xv = (half == 0) ? Xr[j] : 0.f;
    for (int t = 0; t < T_; ++t) {
        float xn = (half == 0 && t < T_ - 1) ? Xr[(size_t)(t + 1) * 512 + j] : 0.f;
        float acc = xv;
        const float4* lh4 = (const float4*)(lh + half * 64);
        #pragma unroll
        for (int i = 0; i < 16; ++i) {
            float4 h4 = lh4[i];
            acc += w[i].x * h4.x + w[i].y * h4.y + w[i].z * h4.z + w[i].w * h4.w;
        }
        lz[tid] = acc;
        __syncthreads();
        if (tid < 128) {
            float zi = lz[tid]       + lz[512 + tid];
            float zf = lz[128 + tid] + lz[640 + tid];
            float zg = lz[256 + tid] + lz[768 + tid];
            float zo = lz[384 + tid] + lz[896 + tid];
            float ig = sigf(zi), fg = sigf(zf);
            float gg = tanhf(zg), og = sigf(zo);
            creg = fg * creg + ig * gg;
            float h = og * tanhf(creg);
            lh[tid] = h;
            out[((size_t)b * T_ + t) * 128 + tid] = h;
        }
        __syncthreads();
        xv = xn;
    }
    if (tid < 128) {
        cf[(size_t)b * 128 + tid] = creg;
        hf[(size_t)b * 128 + tid] = lh[tid];
    }
}

// ---------------------------------------------------------------- split-K reduce + bias
__global__ __launch_bounds__(256) void reduce_kernel(
    const float* __restrict__ part, const float* __restrict__ bias,
    float* __restrict__ d)
{
    int i = blockIdx.x * 256 + threadIdx.x;   // 0..131071
    float s = bias[i & 511];
    #pragma unroll
    for (int p = 0; p < 16; ++p) s += part[(size_t)p * 131072 + i];
    d[i] = s;
}

// ---------------------------------------------------------------- BatchNorm (batch stats) + leaky
__global__ __launch_bounds__(256) void bn_kernel(
    float* __restrict__ d, const float* __restrict__ scale, const float* __restrict__ bias)
{
    int j = blockIdx.x * 256 + threadIdx.x;   // column 0..511
    float s = 0.f, s2 = 0.f;
    for (int m = 0; m < 256; ++m) {
        float v = d[(size_t)m * 512 + j];
        s += v; s2 += v * v;
    }
    float mean = s * (1.f / 256.f);
    float var  = s2 * (1.f / 256.f) - mean * mean;
    float inv  = rsqrtf(var + 1e-5f);
    float sc = scale[j] * inv;
    float bi = bias[j] - mean * sc;
    for (int m = 0; m < 256; ++m) {
        float v = d[(size_t)m * 512 + j] * sc + bi;
        d[(size_t)m * 512 + j] = leakyf(v);
    }
}

// ---------------------------------------------------------------- head GEMV + softmax
__global__ __launch_bounds__(64) void head_kernel(
    const float* __restrict__ d, const float* __restrict__ Wd2,
    const float* __restrict__ bd2, float* __restrict__ out)
{
    int r = blockIdx.x, l = threadIdx.x;
    float acc[10] = {};
    for (int k = l; k < 512; k += 64) {
        float v = d[(size_t)r * 512 + k];
        #pragma unroll
        for (int n = 0; n < 10; ++n) acc[n] += v * Wd2[k * 10 + n];
    }
    #pragma unroll
    for (int n = 0; n < 10; ++n)
        for (int off = 32; off; off >>= 1) acc[n] += __shfl_down(acc[n], off);
    if (l == 0) {
        float mx = -1e30f;
        #pragma unroll
        for (int n = 0; n < 10; ++n) { acc[n] += bd2[n]; mx = fmaxf(mx, acc[n]); }
        float s = 0.f;
        #pragma unroll
        for (int n = 0; n < 10; ++n) { acc[n] = expf(acc[n] - mx); s += acc[n]; }
        float invs = 1.f / s;
        #pragma unroll
        for (int n = 0; n < 10; ++n) out[(size_t)r * 10 + n] = acc[n] * invs;
    }
}

// ----------------------------------------------------------------
extern "C" void kernel_launch(void* const* d_in, const int* in_sizes, int n_in,
                              void* d_out, int out_size, void* d_ws, size_t ws_size,
                              hipStream_t stream)
{
    const float* x   = (const float*)d_in[0];
    const float* W1  = (const float*)d_in[1];
    const float* bc1 = (const float*)d_in[2];
    const float* W2  = (const float*)d_in[3];
    const float* bc2 = (const float*)d_in[4];
    const float* W3  = (const float*)d_in[5];
    const float* bc3 = (const float*)d_in[6];
    const float* Wx1 = (const float*)d_in[7];
    const float* Wh1 = (const float*)d_in[8];
    const float* b1  = (const float*)d_in[9];
    const float* Wx2 = (const float*)d_in[10];
    const float* Wh2 = (const float*)d_in[11];
    const float* b2  = (const float*)d_in[12];
    const float* Wd1 = (const float*)d_in[13];
    const float* bd1 = (const float*)d_in[14];
    const float* bns = (const float*)d_in[15];
    const float* bnb = (const float*)d_in[16];
    const float* Wd2 = (const float*)d_in[17];
    const float* bd2 = (const float*)d_in[18];
    float* outp = (float*)d_out;

    const size_t BT = (size_t)B_ * T_;
    float* ws   = (float*)d_ws;
    float* bufA = ws;                               // BT*512 floats: a2(bf16)+a1 -> X1 -> X2 -> dense partials
    __hip_bfloat16* a2 = (__hip_bfloat16*)bufA;     // BT*512 bf16 (first half of bufA)
    float* a1   = bufA + BT * 256;                  // BT*32 floats (tail of bufA, disjoint from a2 bytes)
    float* bufC = bufA + BT * 512;                  // BT*128: a3 -> out2
    float* bufD = bufC + BT * 128;                  // BT*128: out1
    float* bufd = bufD + BT * 128;                  // 256*512
    float* cfb  = bufd + (size_t)256 * 512;
    float* hfb  = cfb + (size_t)B_ * HLS;
    float* WhT1 = hfb + (size_t)B_ * HLS;           // 512*128
    float* WhT2 = WhT1 + 512 * 128;                 // 512*128
    __hip_bfloat16* W3T = (__hip_bfloat16*)(WhT2 + 512 * 128);  // 5*128*512 bf16
    float* bufP = bufA;                              // dense split-K partials (16*131072 floats)

    // weight prep
    prep_wht<<<dim3(256), dim3(256), 0, stream>>>(Wh1, WhT1);
    prep_wht<<<dim3(256), dim3(256), 0, stream>>>(Wh2, WhT2);
    prep_w3t<<<dim3(1280), dim3(256), 0, stream>>>(W3, W3T);

    // convs
    conv1_kernel<<<dim3(B_ * T_ / 8), dim3(256), 0, stream>>>(x, W1, bc1, a1);
    conv2_kernel<<<dim3(B_ * T_ / 16), dim3(256), 0, stream>>>(a1, W2, bc2, a2);
    conv3_mfma<<<dim3(B_ * T_ / 64), dim3(256), 0, stream>>>(a2, W3T, bc3, bufC);

    // X1 = a3 @ Wx1 + b1
    gemm_kernel<<<dim3(1024, 8, 1), dim3(256), 0, stream>>>(bufC, Wx1, b1, bufA, 65536, 512, 128, 128);
    lstm2_kernel<<<dim3(256), dim3(1024), 0, stream>>>(bufA, WhT1, nullptr, nullptr, bufD, cfb, hfb, 1);
    // X2 = out1 @ Wx2 + b2
    gemm_kernel<<<dim3(1024, 8, 1), dim3(256), 0, stream>>>(bufD, Wx2, b2, bufA, 65536, 512, 128, 128);
    lstm2_kernel<<<dim3(256), dim3(1024), 0, stream>>>(bufA, WhT2, cfb, hfb, bufC, cfb, hfb, 0);

    // dense: [256, 32768] @ [32768, 512], split-K 16 x 2048
    gemm_kernel<<<dim3(4, 8, 16), dim3(256), 0, stream>>>(bufC, Wd1, nullptr, bufP, 256, 512, 32768, 2048);
    reduce_kernel<<<dim3(512), dim3(256), 0, stream>>>(bufP, bd1, bufd);

    bn_kernel<<<dim3(2), dim3(256), 0, stream>>>(bufd, bns, bnb);
    head_kernel<<<dim3(256), dim3(64), 0, stream>>>(bufd, Wd2, bd2, outp);
}

// Round 3
// 1145.788 us; speedup vs baseline: 2.8731x; 1.3113x over previous
//
#include <hip/hip_runtime.h>
#include <hip/hip_bf16.h>
#include <math.h>

#define B_ 256
#define T_ 256
#define HLS 128

typedef __bf16 bf16x8 __attribute__((ext_vector_type(8)));
typedef float f32x4 __attribute__((ext_vector_type(4)));
typedef unsigned int u32x4 __attribute__((ext_vector_type(4)));

__device__ __forceinline__ float leakyf(float v) { return v > 0.f ? v : 0.01f * v; }
__device__ __forceinline__ float sigfast(float x) { return __builtin_amdgcn_rcpf(1.f + __expf(-x)); }
__device__ __forceinline__ float tanhfast(float x) {
    float e = __expf(2.f * x);
    return 1.f - 2.f * __builtin_amdgcn_rcpf(e + 1.f);
}

// ---------------------------------------------------------------- conv1: [B,T,8] -> [B,T,32] bf16
__global__ __launch_bounds__(256) void conv1_kernel(
    const float* __restrict__ x, const float* __restrict__ W,
    const float* __restrict__ bias, __hip_bfloat16* __restrict__ out)
{
    int tid  = threadIdx.x;
    int co   = tid & 31;
    int tsub = tid >> 5;
    int b    = blockIdx.x >> 5;
    int t    = ((blockIdx.x & 31) << 3) + tsub;
    float acc = bias[co];
    #pragma unroll
    for (int k = 0; k < 5; ++k) {
        int tt = t + k - 2;
        if (tt < 0 || tt >= T_) continue;
        const float* xr = x + ((size_t)b * T_ + tt) * 8;
        #pragma unroll
        for (int ci = 0; ci < 8; ++ci)
            acc += xr[ci] * W[(k * 8 + ci) * 32 + co];
    }
    out[((size_t)b * T_ + t) * 32 + co] = __float2bfloat16(leakyf(acc));
}

// ---------------------------------------------------------------- weight preps
// [128][512] fp32 -> [512][128] bf16 (Wh and Wx)
__global__ __launch_bounds__(256) void prep_T128(const float* __restrict__ in, __hip_bfloat16* __restrict__ out)
{
    int idx = blockIdx.x * 256 + threadIdx.x;     // 0..65535
    int k = idx >> 9, n = idx & 511;
    out[n * 128 + k] = __float2bfloat16(in[idx]);
}
// W2[5][32][512] fp32 -> W2T[512][160] bf16
__global__ __launch_bounds__(256) void prep_w2T(const float* __restrict__ in, __hip_bfloat16* __restrict__ out)
{
    int idx = blockIdx.x * 256 + threadIdx.x;     // 0..81919
    int n = idx & 511, r = idx >> 9;
    int ci = r & 31, kt = r >> 5;
    out[n * 160 + kt * 32 + ci] = __float2bfloat16(in[idx]);
}
// W3[5,512,128] fp32 -> W3T[5,128,512] bf16
__global__ __launch_bounds__(256) void prep_w3t(const float* __restrict__ W3, __hip_bfloat16* __restrict__ W3T)
{
    int idx = blockIdx.x * 256 + threadIdx.x;     // 0..327679
    int co = idx & 127, rest = idx >> 7;
    int ci = rest & 511, k = rest >> 9;
    W3T[((size_t)(k * 128 + co)) * 512 + ci] = __float2bfloat16(W3[idx]);
}
// Wd1[32768][512] fp32 -> WdT[512][32768] bf16 via LDS tile transpose
__global__ __launch_bounds__(256) void twd_kernel(const float* __restrict__ Wd1, __hip_bfloat16* __restrict__ WdT)
{
    __shared__ float tile[64][65];
    int tid = threadIdx.x;
    int k0 = blockIdx.x * 64, n0 = blockIdx.y * 64;
    for (int i = tid; i < 4096; i += 256) {
        int k = i >> 6, n = i & 63;
        tile[k][n] = Wd1[(size_t)(k0 + k) * 512 + n0 + n];
    }
    __syncthreads();
    for (int i = tid; i < 4096; i += 256) {
        int n = i >> 6, k = i & 63;
        WdT[(size_t)(n0 + n) * 32768 + k0 + k] = __float2bfloat16(tile[k][n]);
    }
}

// ---------------------------------------------------------------- conv2 MFMA: [B,T,32]bf16 -> [B,T,512]bf16
__global__ __launch_bounds__(256) void conv2_mfma(
    const __hip_bfloat16* __restrict__ a1,   // [B*T][32]
    const __hip_bfloat16* __restrict__ W2T,  // [512][160]
    const float* __restrict__ bias, __hip_bfloat16* __restrict__ out)
{
    const int tid = threadIdx.x, l = tid & 63, w = tid >> 6;
    const int lr = l & 15, lg = l >> 4;
    const int b  = blockIdx.x >> 2;
    const int t0 = ((blockIdx.x & 3) << 6) + w * 16;

    f32x4 acc[32];
    #pragma unroll
    for (int q = 0; q < 32; ++q) acc[q] = (f32x4){0.f, 0.f, 0.f, 0.f};

    for (int kt = 0; kt < 5; ++kt) {
        int tt = t0 + lr + kt - 2;
        u32x4 au = {0u, 0u, 0u, 0u};
        if (tt >= 0 && tt < T_) au = *(const u32x4*)&a1[((size_t)b * T_ + tt) * 32 + lg * 8];
        bf16x8 af = __builtin_bit_cast(bf16x8, au);
        #pragma unroll
        for (int q = 0; q < 32; ++q) {
            bf16x8 bf = *(const bf16x8*)&W2T[(size_t)(q * 16 + lr) * 160 + kt * 32 + lg * 8];
            acc[q] = __builtin_amdgcn_mfma_f32_16x16x32_bf16(af, bf, acc[q], 0, 0, 0);
        }
    }
    #pragma unroll
    for (int q = 0; q < 32; ++q) {
        int co = q * 16 + lr;
        float bb = bias[co];
        #pragma unroll
        for (int r = 0; r < 4; ++r) {
            int t = t0 + lg * 4 + r;
            out[((size_t)b * T_ + t) * 512 + co] = __float2bfloat16(leakyf(acc[q][r] + bb));
        }
    }
}

// ---------------------------------------------------------------- conv3 MFMA: [B,T,512]bf16 -> [B,T,128]bf16
__global__ __launch_bounds__(256) void conv3_mfma(
    const __hip_bfloat16* __restrict__ a2,   // [B,T,512] bf16
    const __hip_bfloat16* __restrict__ W3T,  // [5,128,512] bf16
    const float* __restrict__ bias, __hip_bfloat16* __restrict__ out)
{
    const int tid = threadIdx.x, lane = tid & 63, wave = tid >> 6;
    const int wm = wave & 1, wn = wave >> 1;
    const int b  = blockIdx.x >> 2;
    const int t0 = (blockIdx.x & 3) << 6;
    const int lr = lane & 15, lg = lane >> 4;

    f32x4 acc[2][4];
    #pragma unroll
    for (int i = 0; i < 2; ++i)
        #pragma unroll
        for (int j = 0; j < 4; ++j) acc[i][j] = (f32x4){0.f, 0.f, 0.f, 0.f};

    const __hip_bfloat16* a2b = a2 + (size_t)b * T_ * 512;

    for (int k = 0; k < 5; ++k) {
        const int r0 = t0 + wm * 32 + lr + k - 2;
        const __hip_bfloat16* wbase = W3T + ((size_t)(k * 128 + wn * 64 + lr)) * 512;
        for (int ci0 = 0; ci0 < 512; ci0 += 32) {
            const int ci = ci0 + lg * 8;
            bf16x8 af[2];
            #pragma unroll
            for (int fm = 0; fm < 2; ++fm) {
                int trow = r0 + fm * 16;
                u32x4 au = {0u, 0u, 0u, 0u};
                if (trow >= 0 && trow < T_)
                    au = *(const u32x4*)(a2b + (size_t)trow * 512 + ci);
                af[fm] = __builtin_bit_cast(bf16x8, au);
            }
            #pragma unroll
            for (int fn = 0; fn < 4; ++fn) {
                bf16x8 bf = *(const bf16x8*)(wbase + (size_t)fn * 16 * 512 + ci);
                acc[0][fn] = __builtin_amdgcn_mfma_f32_16x16x32_bf16(af[0], bf, acc[0][fn], 0, 0, 0);
                acc[1][fn] = __builtin_amdgcn_mfma_f32_16x16x32_bf16(af[1], bf, acc[1][fn], 0, 0, 0);
            }
        }
    }
    #pragma unroll
    for (int fm = 0; fm < 2; ++fm)
        #pragma unroll
        for (int fn = 0; fn < 4; ++fn) {
            int co = wn * 64 + fn * 16 + lr;
            float bb = bias[co];
            #pragma unroll
            for (int r = 0; r < 4; ++r) {
                int t = t0 + wm * 32 + fm * 16 + lg * 4 + r;
                out[((size_t)b * T_ + t) * 128 + co] = __float2bfloat16(leakyf(acc[fm][fn][r] + bb));
            }
        }
}

// ---------------------------------------------------------------- unified bf16 MFMA GEMM: C[M,512] = A[M,K] @ BT[512,K]^T (+bias)
// split-K via blockIdx.z (klen per chunk), partial C planes of M*512
__global__ __launch_bounds__(512) void gemm_mfma(
    const __hip_bfloat16* __restrict__ A,
    const __hip_bfloat16* __restrict__ BT,
    const float* __restrict__ bias,
    float* __restrict__ C,
    int K, int klen)
{
    const int tid = threadIdx.x, l = tid & 63, w = tid >> 6;
    const int lr = l & 15, lg = l >> 4;
    const size_t m0 = (size_t)blockIdx.x * 128 + w * 16;
    const int k0 = blockIdx.z * klen;
    C += (size_t)blockIdx.z * gridDim.x * 128 * 512;

    f32x4 acc[32];
    #pragma unroll
    for (int q = 0; q < 32; ++q) acc[q] = (f32x4){0.f, 0.f, 0.f, 0.f};

    const __hip_bfloat16* Arow  = A + (m0 + lr) * (size_t)K + k0 + lg * 8;
    const __hip_bfloat16* Bbase = BT + (size_t)lr * K + k0 + lg * 8;

    const int nkf = klen >> 5;
    for (int kf = 0; kf < nkf; ++kf) {
        bf16x8 af = *(const bf16x8*)(Arow + kf * 32);
        #pragma unroll
        for (int q = 0; q < 32; ++q) {
            bf16x8 bf = *(const bf16x8*)(Bbase + (size_t)q * 16 * K + kf * 32);
            acc[q] = __builtin_amdgcn_mfma_f32_16x16x32_bf16(af, bf, acc[q], 0, 0, 0);
        }
    }
    #pragma unroll
    for (int q = 0; q < 32; ++q) {
        int n = q * 16 + lr;
        float bb = bias ? bias[n] : 0.f;
        #pragma unroll
        for (int r = 0; r < 4; ++r) {
            size_t m = m0 + lg * 4 + r;
            C[m * 512 + n] = acc[q][r] + bb;
        }
    }
}

// ---------------------------------------------------------------- LSTM via MFMA: 4 batch rows/block, 8 waves
__global__ __launch_bounds__(512) void lstm_mfma(
    const float* __restrict__ X,             // [B,T,512] fp32 (x@Wx+b)
    const __hip_bfloat16* __restrict__ WhT,  // [512][128] bf16
    const float* __restrict__ cin,           // [B,128] or null
    const __hip_bfloat16* __restrict__ hin,  // out1 [B,T,128] (take t=255) or null
    __hip_bfloat16* __restrict__ out,        // [B,T,128] bf16
    float* __restrict__ cf, int initZero)
{
    __shared__ __hip_bfloat16 lh[16 * 128];  // h matrix, rows 4-15 zero, XOR-swizzled
    __shared__ float zl[16 * 516];
    const int tid = threadIdx.x, l = tid & 63, g = tid >> 6;  // wave id 0..7
    const int lr = l & 15, lg = l >> 4;
    const int b0 = blockIdx.x * 4;

    // preload Wh fragments: wave g owns gate-tiles n0 = q*128 + g*16
    bf16x8 wb[4][4];
    #pragma unroll
    for (int q = 0; q < 4; ++q)
        #pragma unroll
        for (int kf = 0; kf < 4; ++kf)
            wb[q][kf] = *(const bf16x8*)&WhT[(size_t)(q * 128 + g * 16 + lr) * 128 + kf * 32 + lg * 8];

    // zero h rows 4..15 (swizzle is a permutation within each row: zero whole rows linearly)
    for (int idx = tid; idx < 12 * 128; idx += 512)
        lh[4 * 128 + idx] = __float2bfloat16(0.f);

    const int grow = tid >> 7;   // 0..3 gate row (batch)
    const int gj   = tid & 127;  // hidden index
    float c;
    {
        __hip_bfloat16 h0;
        if (initZero) { c = 0.f; h0 = __float2bfloat16(0.f); }
        else {
            c  = cin[(size_t)(b0 + grow) * 128 + gj];
            h0 = hin[((size_t)(b0 + grow) * T_ + (T_ - 1)) * 128 + gj];
        }
        lh[grow * 128 + (((gj >> 3) ^ grow) << 3) + (gj & 7)] = h0;
    }
    __syncthreads();

    const float* Xg = X + ((size_t)(b0 + grow) * T_) * 512 + gj;
    float xv0 = Xg[0], xv1 = Xg[128], xv2 = Xg[256], xv3 = Xg[384];

    for (int t = 0; t < T_; ++t) {
        float xn0 = 0.f, xn1 = 0.f, xn2 = 0.f, xn3 = 0.f;
        if (t < T_ - 1) {
            const float* Xp = Xg + (size_t)(t + 1) * 512;
            xn0 = Xp[0]; xn1 = Xp[128]; xn2 = Xp[256]; xn3 = Xp[384];
        }
        // A fragments from swizzled lh (identical across waves)
        bf16x8 af[4];
        #pragma unroll
        for (int kf = 0; kf < 4; ++kf) {
            int chunk = (kf * 4 + lg) ^ (lr & 7);
            af[kf] = *(const bf16x8*)&lh[lr * 128 + chunk * 8];
        }
        #pragma unroll
        for (int q = 0; q < 4; ++q) {
            f32x4 acc = (f32x4){0.f, 0.f, 0.f, 0.f};
            #pragma unroll
            for (int kf = 0; kf < 4; ++kf)
                acc = __builtin_amdgcn_mfma_f32_16x16x32_bf16(af[kf], wb[q][kf], acc, 0, 0, 0);
            int n = q * 128 + g * 16 + lr;
            if (lg == 0) {                    // only rows 0..3 are real
                #pragma unroll
                for (int r = 0; r < 4; ++r)
                    zl[r * 516 + n] = acc[r];
            }
        }
        __syncthreads();
        {
            float zi = zl[grow * 516 + gj]        + xv0;
            float zf = zl[grow * 516 + 128 + gj]  + xv1;
            float zg = zl[grow * 516 + 256 + gj]  + xv2;
            float zo = zl[grow * 516 + 384 + gj]  + xv3;
            float ig = sigfast(zi), fg = sigfast(zf);
            float gg = tanhfast(zg), og = sigfast(zo);
            c = fg * c + ig * gg;
            float h = og * tanhfast(c);
            __hip_bfloat16 hb = __float2bfloat16(h);
            lh[grow * 128 + (((gj >> 3) ^ grow) << 3) + (gj & 7)] = hb;
            out[((size_t)(b0 + grow) * T_ + t) * 128 + gj] = hb;
        }
        __syncthreads();
        xv0 = xn0; xv1 = xn1; xv2 = xn2; xv3 = xn3;
    }
    cf[(size_t)(b0 + grow) * 128 + gj] = c;
}

// ---------------------------------------------------------------- split-K reduce (64 partials) + bias
__global__ __launch_bounds__(256) void reduce_kernel(
    const float* __restrict__ part, const float* __restrict__ bias,
    float* __restrict__ d)
{
    int i = blockIdx.x * 256 + threadIdx.x;   // 0..131071
    float s = bias[i & 511];
    #pragma unroll
    for (int p = 0; p < 64; ++p) s += part[(size_t)p * 131072 + i];
    d[i] = s;
}

// ---------------------------------------------------------------- BatchNorm (batch stats) + leaky
__global__ __launch_bounds__(256) void bn_kernel(
    float* __restrict__ d, const float* __restrict__ scale, const float* __restrict__ bias)
{
    int j = blockIdx.x * 256 + threadIdx.x;
    float s = 0.f, s2 = 0.f;
    for (int m = 0; m < 256; ++m) {
        float v = d[(size_t)m * 512 + j];
        s += v; s2 += v * v;
    }
    float mean = s * (1.f / 256.f);
    float var  = s2 * (1.f / 256.f) - mean * mean;
    float inv  = rsqrtf(var + 1e-5f);
    float sc = scale[j] * inv;
    float bi = bias[j] - mean * sc;
    for (int m = 0; m < 256; ++m) {
        float v = d[(size_t)m * 512 + j] * sc + bi;
        d[(size_t)m * 512 + j] = leakyf(v);
    }
}

// ---------------------------------------------------------------- head GEMV + softmax
__global__ __launch_bounds__(64) void head_kernel(
    const float* __restrict__ d, const float* __restrict__ Wd2,
    const float* __restrict__ bd2, float* __restrict__ out)
{
    int r = blockIdx.x, l = threadIdx.x;
    float acc[10] = {};
    for (int k = l; k < 512; k += 64) {
        float v = d[(size_t)r * 512 + k];
        #pragma unroll
        for (int n = 0; n < 10; ++n) acc[n] += v * Wd2[k * 10 + n];
    }
    #pragma unroll
    for (int n = 0; n < 10; ++n)
        for (int off = 32; off; off >>= 1) acc[n] += __shfl_down(acc[n], off);
    if (l == 0) {
        float mx = -1e30f;
        #pragma unroll
        for (int n = 0; n < 10; ++n) { acc[n] += bd2[n]; mx = fmaxf(mx, acc[n]); }
        float s = 0.f;
        #pragma unroll
        for (int n = 0; n < 10; ++n) { acc[n] = expf(acc[n] - mx); s += acc[n]; }
        float invs = 1.f / s;
        #pragma unroll
        for (int n = 0; n < 10; ++n) out[(size_t)r * 10 + n] = acc[n] * invs;
    }
}

// ----------------------------------------------------------------
extern "C" void kernel_launch(void* const* d_in, const int* in_sizes, int n_in,
                              void* d_out, int out_size, void* d_ws, size_t ws_size,
                              hipStream_t stream)
{
    const float* x   = (const float*)d_in[0];
    const float* W1  = (const float*)d_in[1];
    const float* bc1 = (const float*)d_in[2];
    const float* W2  = (const float*)d_in[3];
    const float* bc2 = (const float*)d_in[4];
    const float* W3  = (const float*)d_in[5];
    const float* bc3 = (const float*)d_in[6];
    const float* Wx1 = (const float*)d_in[7];
    const float* Wh1 = (const float*)d_in[8];
    const float* b1  = (const float*)d_in[9];
    const float* Wx2 = (const float*)d_in[10];
    const float* Wh2 = (const float*)d_in[11];
    const float* b2  = (const float*)d_in[12];
    const float* Wd1 = (const float*)d_in[13];
    const float* bd1 = (const float*)d_in[14];
    const float* bns = (const float*)d_in[15];
    const float* bnb = (const float*)d_in[16];
    const float* Wd2 = (const float*)d_in[17];
    const float* bd2 = (const float*)d_in[18];
    float* outp = (float*)d_out;

    const size_t BT = (size_t)B_ * T_;
    float* ws   = (float*)d_ws;
    float* bufA = ws;                         // BT*512 f: a2(bf16)+a1(bf16) -> X1 -> X2 -> dense partials
    float* bufC = bufA + BT * 512;            // BT*128 f: a3(bf16) -> out2(bf16)
    float* bufD = bufC + BT * 128;            // BT*128 f: out1(bf16) -> WdT(bf16)
    float* bufd = bufD + BT * 128;            // 131072 f
    float* cfb  = bufd + 131072;              // 32768 f
    __hip_bfloat16* WhT1b = (__hip_bfloat16*)(cfb + 32768);
    __hip_bfloat16* WhT2b = WhT1b + 65536;
    __hip_bfloat16* WxT1b = WhT2b + 65536;
    __hip_bfloat16* WxT2b = WxT1b + 65536;
    __hip_bfloat16* W2Tb  = WxT2b + 65536;    // 81920 bf16
    __hip_bfloat16* W3Tb  = W2Tb + 81920;     // 327680 bf16

    __hip_bfloat16* a2b   = (__hip_bfloat16*)bufA;
    __hip_bfloat16* a1b   = (__hip_bfloat16*)(bufA + BT * 256);
    __hip_bfloat16* a3b   = (__hip_bfloat16*)bufC;
    __hip_bfloat16* out1b = (__hip_bfloat16*)bufD;
    __hip_bfloat16* out2b = (__hip_bfloat16*)bufC;
    __hip_bfloat16* WdTb  = (__hip_bfloat16*)bufD;

    // weight preps
    prep_T128<<<dim3(256), dim3(256), 0, stream>>>(Wh1, WhT1b);
    prep_T128<<<dim3(256), dim3(256), 0, stream>>>(Wh2, WhT2b);
    prep_T128<<<dim3(256), dim3(256), 0, stream>>>(Wx1, WxT1b);
    prep_T128<<<dim3(256), dim3(256), 0, stream>>>(Wx2, WxT2b);
    prep_w2T<<<dim3(320), dim3(256), 0, stream>>>(W2, W2Tb);
    prep_w3t<<<dim3(1280), dim3(256), 0, stream>>>(W3, W3Tb);

    // convs
    conv1_kernel<<<dim3(B_ * T_ / 8), dim3(256), 0, stream>>>(x, W1, bc1, a1b);
    conv2_mfma<<<dim3(B_ * T_ / 64), dim3(256), 0, stream>>>(a1b, W2Tb, bc2, a2b);
    conv3_mfma<<<dim3(B_ * T_ / 64), dim3(256), 0, stream>>>(a2b, W3Tb, bc3, a3b);

    // X1 = a3 @ Wx1 + b1 (fp32 out)
    gemm_mfma<<<dim3(512, 1, 1), dim3(512), 0, stream>>>(a3b, WxT1b, b1, bufA, 128, 128);
    lstm_mfma<<<dim3(64), dim3(512), 0, stream>>>(bufA, WhT1b, nullptr, nullptr, out1b, cfb, 1);
    // X2 = out1 @ Wx2 + b2
    gemm_mfma<<<dim3(512, 1, 1), dim3(512), 0, stream>>>(out1b, WxT2b, b2, bufA, 128, 128);
    lstm_mfma<<<dim3(64), dim3(512), 0, stream>>>(bufA, WhT2b, cfb, out1b, out2b, cfb, 0);

    // Wd1 transpose into bufD (out1 dead after lstm2 start; stream is serial)
    twd_kernel<<<dim3(512, 8), dim3(256), 0, stream>>>(Wd1, WdTb);
    // dense: [256, 32768] @ WdT, split-K 64 x 512 -> partials in bufA
    gemm_mfma<<<dim3(2, 1, 64), dim3(512), 0, stream>>>(out2b, WdTb, nullptr, bufA, 32768, 512);
    reduce_kernel<<<dim3(512), dim3(256), 0, stream>>>(bufA, bd1, bufd);

    bn_kernel<<<dim3(2), dim3(256), 0, stream>>>(bufd, bns, bnb);
    head_kernel<<<dim3(256), dim3(64), 0, stream>>>(bufd, Wd2, bd2, outp);
}

// Round 4
// 1097.368 us; speedup vs baseline: 2.9998x; 1.0441x over previous
//
#include <hip/hip_runtime.h>
#include <hip/hip_bf16.h>
#include <math.h>

#define B_ 256
#define T_ 256
#define HLS 128

typedef __bf16 bf16x8 __attribute__((ext_vector_type(8)));
typedef float f32x4 __attribute__((ext_vector_type(4)));
typedef unsigned int u32x4 __attribute__((ext_vector_type(4)));

__device__ __forceinline__ float leakyf(float v) { return v > 0.f ? v : 0.01f * v; }
__device__ __forceinline__ float sigfast(float x) { return __builtin_amdgcn_rcpf(1.f + __expf(-x)); }
__device__ __forceinline__ float tanhfast(float x) {
    float e = __expf(2.f * x);
    return 1.f - 2.f * __builtin_amdgcn_rcpf(e + 1.f);
}

// ---------------------------------------------------------------- conv1: [B,T,8] -> [B,T,32] bf16
__global__ __launch_bounds__(256) void conv1_kernel(
    const float* __restrict__ x, const float* __restrict__ W,
    const float* __restrict__ bias, __hip_bfloat16* __restrict__ out)
{
    int tid  = threadIdx.x;
    int co   = tid & 31;
    int tsub = tid >> 5;
    int b    = blockIdx.x >> 5;
    int t    = ((blockIdx.x & 31) << 3) + tsub;
    float acc = bias[co];
    #pragma unroll
    for (int k = 0; k < 5; ++k) {
        int tt = t + k - 2;
        if (tt < 0 || tt >= T_) continue;
        const float* xr = x + ((size_t)b * T_ + tt) * 8;
        #pragma unroll
        for (int ci = 0; ci < 8; ++ci)
            acc += xr[ci] * W[(k * 8 + ci) * 32 + co];
    }
    out[((size_t)b * T_ + t) * 32 + co] = __float2bfloat16(leakyf(acc));
}

// ---------------------------------------------------------------- weight preps
// 4x: [128][512] fp32 -> [512][128] bf16 (Wh1, Wh2, Wx1, Wx2)
__global__ __launch_bounds__(256) void prep_T128x4(
    const float* __restrict__ i0, const float* __restrict__ i1,
    const float* __restrict__ i2, const float* __restrict__ i3,
    __hip_bfloat16* __restrict__ o0, __hip_bfloat16* __restrict__ o1,
    __hip_bfloat16* __restrict__ o2, __hip_bfloat16* __restrict__ o3)
{
    int which = blockIdx.x >> 8;
    int idx = (blockIdx.x & 255) * 256 + threadIdx.x;   // 0..65535
    int k = idx >> 9, n = idx & 511;
    const float* in = which == 0 ? i0 : which == 1 ? i1 : which == 2 ? i2 : i3;
    __hip_bfloat16* out = which == 0 ? o0 : which == 1 ? o1 : which == 2 ? o2 : o3;
    out[n * 128 + k] = __float2bfloat16(in[idx]);
}
// W2[5][32][512] fp32 -> W2T[512][160] bf16
__global__ __launch_bounds__(256) void prep_w2T(const float* __restrict__ in, __hip_bfloat16* __restrict__ out)
{
    int idx = blockIdx.x * 256 + threadIdx.x;     // 0..81919
    int n = idx & 511, r = idx >> 9;
    int ci = r & 31, kt = r >> 5;
    out[n * 160 + kt * 32 + ci] = __float2bfloat16(in[idx]);
}
// W3[5,512,128] fp32 -> W3T[5,128,512] bf16
__global__ __launch_bounds__(256) void prep_w3t(const float* __restrict__ W3, __hip_bfloat16* __restrict__ W3T)
{
    int idx = blockIdx.x * 256 + threadIdx.x;     // 0..327679
    int co = idx & 127, rest = idx >> 7;
    int ci = rest & 511, k = rest >> 9;
    W3T[((size_t)(k * 128 + co)) * 512 + ci] = __float2bfloat16(W3[idx]);
}
// Wd1[32768,512] fp32 -> WdT[512][32768] bf16 via LDS tile transpose
__global__ __launch_bounds__(256) void twd_kernel(const float* __restrict__ Wd1, __hip_bfloat16* __restrict__ WdT)
{
    __shared__ float tile[64][65];
    int tid = threadIdx.x;
    int k0 = blockIdx.x * 64, n0 = blockIdx.y * 64;
    for (int i = tid; i < 4096; i += 256) {
        int k = i >> 6, n = i & 63;
        tile[k][n] = Wd1[(size_t)(k0 + k) * 512 + n0 + n];
    }
    __syncthreads();
    for (int i = tid; i < 4096; i += 256) {
        int n = i >> 6, k = i & 63;
        WdT[(size_t)(n0 + n) * 32768 + k0 + k] = __float2bfloat16(tile[k][n]);
    }
}

// ---------------------------------------------------------------- conv2 MFMA: [B,T,32]bf16 -> [B,T,512]bf16
__global__ __launch_bounds__(256) void conv2_mfma(
    const __hip_bfloat16* __restrict__ a1,   // [B*T][32]
    const __hip_bfloat16* __restrict__ W2T,  // [512][160]
    const float* __restrict__ bias, __hip_bfloat16* __restrict__ out)
{
    const int tid = threadIdx.x, l = tid & 63, w = tid >> 6;
    const int lr = l & 15, lg = l >> 4;
    const int b  = blockIdx.x >> 2;
    const int t0 = ((blockIdx.x & 3) << 6) + w * 16;

    f32x4 acc[32];
    #pragma unroll
    for (int q = 0; q < 32; ++q) acc[q] = (f32x4){0.f, 0.f, 0.f, 0.f};

    for (int kt = 0; kt < 5; ++kt) {
        int tt = t0 + lr + kt - 2;
        u32x4 au = {0u, 0u, 0u, 0u};
        if (tt >= 0 && tt < T_) au = *(const u32x4*)&a1[((size_t)b * T_ + tt) * 32 + lg * 8];
        bf16x8 af = __builtin_bit_cast(bf16x8, au);
        #pragma unroll
        for (int q = 0; q < 32; ++q) {
            bf16x8 bf = *(const bf16x8*)&W2T[(size_t)(q * 16 + lr) * 160 + kt * 32 + lg * 8];
            acc[q] = __builtin_amdgcn_mfma_f32_16x16x32_bf16(af, bf, acc[q], 0, 0, 0);
        }
    }
    #pragma unroll
    for (int q = 0; q < 32; ++q) {
        int co = q * 16 + lr;
        float bb = bias[co];
        #pragma unroll
        for (int r = 0; r < 4; ++r) {
            int t = t0 + lg * 4 + r;
            out[((size_t)b * T_ + t) * 512 + co] = __float2bfloat16(leakyf(acc[q][r] + bb));
        }
    }
}

// ---------------------------------------------------------------- conv3 MFMA, LDS-staged input tile
// block: 32 t-rows x 128 co. LDS tile 36 rows x 512 ci, XOR-swizzled 16B chunks.
__global__ __launch_bounds__(256) void conv3_mfma(
    const __hip_bfloat16* __restrict__ a2,   // [B,T,512] bf16
    const __hip_bfloat16* __restrict__ W3T,  // [5,128,512] bf16
    const float* __restrict__ bias, __hip_bfloat16* __restrict__ out)
{
    __shared__ __align__(16) unsigned short lin[36 * 512];   // 36 KB
    const int tid = threadIdx.x, lane = tid & 63, wave = tid >> 6;
    const int wm = wave & 1, wn = wave >> 1;
    const int b  = blockIdx.x >> 3;
    const int t0 = (blockIdx.x & 7) << 5;
    const int lr = lane & 15, lg = lane >> 4;

    // stage rows t0-2 .. t0+33 (coalesced, swizzled dest)
    for (int i = tid; i < 36 * 64; i += 256) {
        int row = i >> 6, c16 = i & 63;
        int t = t0 - 2 + row;
        u32x4 v = {0u, 0u, 0u, 0u};
        if (t >= 0 && t < T_) v = *(const u32x4*)&a2[((size_t)b * T_ + t) * 512 + c16 * 8];
        *(u32x4*)&lin[row * 512 + ((c16 ^ (row & 7)) << 3)] = v;
    }
    __syncthreads();

    f32x4 acc[4];
    #pragma unroll
    for (int j = 0; j < 4; ++j) acc[j] = (f32x4){0.f, 0.f, 0.f, 0.f};

    for (int k = 0; k < 5; ++k) {
        const int lrow = wm * 16 + lr + k;          // local row in lin
        const __hip_bfloat16* wbase = W3T + ((size_t)(k * 128 + wn * 64 + lr)) * 512;
        #pragma unroll 4
        for (int ci0 = 0; ci0 < 512; ci0 += 32) {
            int c16 = (ci0 >> 3) + lg;
            bf16x8 af = *(const bf16x8*)&lin[lrow * 512 + ((c16 ^ (lrow & 7)) << 3)];
            #pragma unroll
            for (int fn = 0; fn < 4; ++fn) {
                bf16x8 bf = *(const bf16x8*)(wbase + (size_t)fn * 16 * 512 + ci0 + lg * 8);
                acc[fn] = __builtin_amdgcn_mfma_f32_16x16x32_bf16(af, bf, acc[fn], 0, 0, 0);
            }
        }
    }
    #pragma unroll
    for (int fn = 0; fn < 4; ++fn) {
        int co = wn * 64 + fn * 16 + lr;
        float bb = bias[co];
        #pragma unroll
        for (int r = 0; r < 4; ++r) {
            int t = t0 + wm * 16 + lg * 4 + r;
            out[((size_t)b * T_ + t) * 128 + co] = __float2bfloat16(leakyf(acc[fn][r] + bb));
        }
    }
}

// ---------------------------------------------------------------- unified bf16 MFMA GEMM: C[M,512] = A[M,K] @ BT[512,K]^T (+bias)
__global__ __launch_bounds__(512) void gemm_mfma(
    const __hip_bfloat16* __restrict__ A,
    const __hip_bfloat16* __restrict__ BT,
    const float* __restrict__ bias,
    float* __restrict__ C,
    int K, int klen)
{
    const int tid = threadIdx.x, l = tid & 63, w = tid >> 6;
    const int lr = l & 15, lg = l >> 4;
    const size_t m0 = (size_t)blockIdx.x * 128 + w * 16;
    const int k0 = blockIdx.z * klen;
    C += (size_t)blockIdx.z * gridDim.x * 128 * 512;

    f32x4 acc[32];
    #pragma unroll
    for (int q = 0; q < 32; ++q) acc[q] = (f32x4){0.f, 0.f, 0.f, 0.f};

    const __hip_bfloat16* Arow  = A + (m0 + lr) * (size_t)K + k0 + lg * 8;
    const __hip_bfloat16* Bbase = BT + (size_t)lr * K + k0 + lg * 8;

    const int nkf = klen >> 5;
    for (int kf = 0; kf < nkf; ++kf) {
        bf16x8 af = *(const bf16x8*)(Arow + kf * 32);
        #pragma unroll
        for (int q = 0; q < 32; ++q) {
            bf16x8 bf = *(const bf16x8*)(Bbase + (size_t)q * 16 * K + kf * 32);
            acc[q] = __builtin_amdgcn_mfma_f32_16x16x32_bf16(af, bf, acc[q], 0, 0, 0);
        }
    }
    #pragma unroll
    for (int q = 0; q < 32; ++q) {
        int n = q * 16 + lr;
        float bb = bias ? bias[n] : 0.f;
        #pragma unroll
        for (int r = 0; r < 4; ++r) {
            size_t m = m0 + lg * 4 + r;
            C[m * 512 + n] = acc[q][r] + bb;
        }
    }
}

// ---------------------------------------------------------------- LSTM via MFMA, in-register gates, 1 barrier/step
// 4 batch rows/block at A-rows {0,4,8,12}; lane (wave g, lr, lg) owns (batch row lg, col g*16+lr)
__global__ __launch_bounds__(512) void lstm_mfma(
    const float* __restrict__ X,             // [B,T,512] fp32 (x@Wx+b)
    const __hip_bfloat16* __restrict__ WhT,  // [512][128] bf16
    const float* __restrict__ cin,           // [B,128] or null
    const __hip_bfloat16* __restrict__ hin,  // prev layer out [B,T,128] (t=T-1) or null
    __hip_bfloat16* __restrict__ out,        // [B,T,128] bf16
    float* __restrict__ cf, int initZero)
{
    __shared__ __align__(16) __hip_bfloat16 lh[2][16 * 128];  // double-buffered h matrix
    const int tid = threadIdx.x, l = tid & 63, g = tid >> 6;  // wave 0..7
    const int lr = l & 15, lg = l >> 4;
    const int b0 = blockIdx.x * 4;
    const int j0 = g * 16 + lr;     // gate column 0..127
    const int hrow = lg * 4;        // A-row for this lane's batch row

    // preload Wh fragments: wave g owns gate tiles n = q*128 + g*16
    bf16x8 wb[4][4];
    #pragma unroll
    for (int q = 0; q < 4; ++q)
        #pragma unroll
        for (int kf = 0; kf < 4; ++kf)
            wb[q][kf] = *(const bf16x8*)&WhT[(size_t)(q * 128 + g * 16 + lr) * 128 + kf * 32 + lg * 8];

    // zero both h buffers
    for (int i = tid; i < 2 * 2048; i += 512) ((__hip_bfloat16*)lh)[i] = __float2bfloat16(0.f);
    __syncthreads();

    float c;
    {
        __hip_bfloat16 h0;
        if (initZero) { c = 0.f; h0 = __float2bfloat16(0.f); }
        else {
            c  = cin[(size_t)(b0 + lg) * 128 + j0];
            h0 = hin[((size_t)(b0 + lg) * T_ + (T_ - 1)) * 128 + j0];
        }
        lh[0][hrow * 128 + ((((j0 >> 3) ^ (hrow & 7)) << 3) | (j0 & 7))] = h0;
    }
    __syncthreads();

    const float* Xl = X + ((size_t)(b0 + lg) * T_) * 512 + j0;
    float xc0 = Xl[0], xc1 = Xl[128], xc2 = Xl[256], xc3 = Xl[384];

    for (int t = 0; t < T_; ++t) {
        float xn0 = 0.f, xn1 = 0.f, xn2 = 0.f, xn3 = 0.f;
        if (t < T_ - 1) {
            const float* Xp = Xl + (size_t)(t + 1) * 512;
            xn0 = Xp[0]; xn1 = Xp[128]; xn2 = Xp[256]; xn3 = Xp[384];
        }
        const int cur = t & 1;
        bf16x8 af[4];
        #pragma unroll
        for (int kf = 0; kf < 4; ++kf) {
            int chunk = (kf * 4 + lg) ^ (lr & 7);
            af[kf] = *(const bf16x8*)&lh[cur][lr * 128 + chunk * 8];
        }
        f32x4 a0 = {0.f,0.f,0.f,0.f}, a1 = {0.f,0.f,0.f,0.f}, a2 = {0.f,0.f,0.f,0.f}, a3 = {0.f,0.f,0.f,0.f};
        #pragma unroll
        for (int kf = 0; kf < 4; ++kf) {
            a0 = __builtin_amdgcn_mfma_f32_16x16x32_bf16(af[kf], wb[0][kf], a0, 0, 0, 0);
            a1 = __builtin_amdgcn_mfma_f32_16x16x32_bf16(af[kf], wb[1][kf], a1, 0, 0, 0);
            a2 = __builtin_amdgcn_mfma_f32_16x16x32_bf16(af[kf], wb[2][kf], a2, 0, 0, 0);
            a3 = __builtin_amdgcn_mfma_f32_16x16x32_bf16(af[kf], wb[3][kf], a3, 0, 0, 0);
        }
        // lane (lr,lg) reg 0 = C[row hrow][col lr] = z[batch lg][gate q][j0]
        float zi = a0[0] + xc0;
        float zf = a1[0] + xc1;
        float zg = a2[0] + xc2;
        float zo = a3[0] + xc3;
        float ig = sigfast(zi), fg = sigfast(zf);
        float gg = tanhfast(zg), og = sigfast(zo);
        c = fg * c + ig * gg;
        float h = og * tanhfast(c);
        __hip_bfloat16 hb = __float2bfloat16(h);
        lh[cur ^ 1][hrow * 128 + ((((j0 >> 3) ^ (hrow & 7)) << 3) | (j0 & 7))] = hb;
        out[((size_t)(b0 + lg) * T_ + t) * 128 + j0] = hb;
        __syncthreads();
        xc0 = xn0; xc1 = xn1; xc2 = xn2; xc3 = xn3;
    }
    cf[(size_t)(b0 + lg) * 128 + j0] = c;
}

// ---------------------------------------------------------------- split-K reduce (64 partials) + bias
__global__ __launch_bounds__(256) void reduce_kernel(
    const float* __restrict__ part, const float* __restrict__ bias,
    float* __restrict__ d)
{
    int i = blockIdx.x * 256 + threadIdx.x;   // 0..131071
    float s = bias[i & 511];
    #pragma unroll
    for (int p = 0; p < 64; ++p) s += part[(size_t)p * 131072 + i];
    d[i] = s;
}

// ---------------------------------------------------------------- BatchNorm (batch stats) + leaky, row-parallel
__global__ __launch_bounds__(256) void bn_kernel(
    float* __restrict__ d, const float* __restrict__ scale, const float* __restrict__ bias)
{
    __shared__ float ss[8][32], ss2[8][32];
    int tid = threadIdx.x;
    int cc = tid & 31, rg = tid >> 5;
    int col = blockIdx.x * 32 + cc;
    float s = 0.f, s2 = 0.f;
    for (int r = rg * 32; r < rg * 32 + 32; ++r) {
        float v = d[(size_t)r * 512 + col];
        s += v; s2 += v * v;
    }
    ss[rg][cc] = s; ss2[rg][cc] = s2;
    __syncthreads();
    float st = 0.f, s2t = 0.f;
    #pragma unroll
    for (int i = 0; i < 8; ++i) { st += ss[i][cc]; s2t += ss2[i][cc]; }
    float mean = st * (1.f / 256.f);
    float var  = s2t * (1.f / 256.f) - mean * mean;
    float inv  = rsqrtf(var + 1e-5f);
    float sc = scale[col] * inv;
    float bi = bias[col] - mean * sc;
    for (int r = rg * 32; r < rg * 32 + 32; ++r) {
        float v = d[(size_t)r * 512 + col] * sc + bi;
        d[(size_t)r * 512 + col] = leakyf(v);
    }
}

// ---------------------------------------------------------------- head GEMV + softmax
__global__ __launch_bounds__(64) void head_kernel(
    const float* __restrict__ d, const float* __restrict__ Wd2,
    const float* __restrict__ bd2, float* __restrict__ out)
{
    int r = blockIdx.x, l = threadIdx.x;
    float acc[10] = {};
    for (int k = l; k < 512; k += 64) {
        float v = d[(size_t)r * 512 + k];
        #pragma unroll
        for (int n = 0; n < 10; ++n) acc[n] += v * Wd2[k * 10 + n];
    }
    #pragma unroll
    for (int n = 0; n < 10; ++n)
        for (int off = 32; off; off >>= 1) acc[n] += __shfl_down(acc[n], off);
    if (l == 0) {
        float mx = -1e30f;
        #pragma unroll
        for (int n = 0; n < 10; ++n) { acc[n] += bd2[n]; mx = fmaxf(mx, acc[n]); }
        float s = 0.f;
        #pragma unroll
        for (int n = 0; n < 10; ++n) { acc[n] = expf(acc[n] - mx); s += acc[n]; }
        float invs = 1.f / s;
        #pragma unroll
        for (int n = 0; n < 10; ++n) out[(size_t)r * 10 + n] = acc[n] * invs;
    }
}

// ----------------------------------------------------------------
extern "C" void kernel_launch(void* const* d_in, const int* in_sizes, int n_in,
                              void* d_out, int out_size, void* d_ws, size_t ws_size,
                              hipStream_t stream)
{
    const float* x   = (const float*)d_in[0];
    const float* W1  = (const float*)d_in[1];
    const float* bc1 = (const float*)d_in[2];
    const float* W2  = (const float*)d_in[3];
    const float* bc2 = (const float*)d_in[4];
    const float* W3  = (const float*)d_in[5];
    const float* bc3 = (const float*)d_in[6];
    const float* Wx1 = (const float*)d_in[7];
    const float* Wh1 = (const float*)d_in[8];
    const float* b1  = (const float*)d_in[9];
    const float* Wx2 = (const float*)d_in[10];
    const float* Wh2 = (const float*)d_in[11];
    const float* b2  = (const float*)d_in[12];
    const float* Wd1 = (const float*)d_in[13];
    const float* bd1 = (const float*)d_in[14];
    const float* bns = (const float*)d_in[15];
    const float* bnb = (const float*)d_in[16];
    const float* Wd2 = (const float*)d_in[17];
    const float* bd2 = (const float*)d_in[18];
    float* outp = (float*)d_out;

    const size_t BT = (size_t)B_ * T_;
    float* ws   = (float*)d_ws;
    float* bufA = ws;                         // BT*512 f: a2(bf16)+a1(bf16) -> X1 -> X2 -> dense partials
    float* bufC = bufA + BT * 512;            // BT*128 f: a3(bf16) -> out2(bf16)
    float* bufD = bufC + BT * 128;            // BT*128 f: out1(bf16) -> WdT(bf16)
    float* bufd = bufD + BT * 128;            // 131072 f
    float* cfb  = bufd + 131072;              // 32768 f
    __hip_bfloat16* WhT1b = (__hip_bfloat16*)(cfb + 32768);
    __hip_bfloat16* WhT2b = WhT1b + 65536;
    __hip_bfloat16* WxT1b = WhT2b + 65536;
    __hip_bfloat16* WxT2b = WxT1b + 65536;
    __hip_bfloat16* W2Tb  = WxT2b + 65536;    // 81920 bf16
    __hip_bfloat16* W3Tb  = W2Tb + 81920;     // 327680 bf16

    __hip_bfloat16* a2b   = (__hip_bfloat16*)bufA;
    __hip_bfloat16* a1b   = (__hip_bfloat16*)(bufA + BT * 256);
    __hip_bfloat16* a3b   = (__hip_bfloat16*)bufC;
    __hip_bfloat16* out1b = (__hip_bfloat16*)bufD;
    __hip_bfloat16* out2b = (__hip_bfloat16*)bufC;
    __hip_bfloat16* WdTb  = (__hip_bfloat16*)bufD;

    // weight preps
    prep_T128x4<<<dim3(1024), dim3(256), 0, stream>>>(Wh1, Wh2, Wx1, Wx2, WhT1b, WhT2b, WxT1b, WxT2b);
    prep_w2T<<<dim3(320), dim3(256), 0, stream>>>(W2, W2Tb);
    prep_w3t<<<dim3(1280), dim3(256), 0, stream>>>(W3, W3Tb);

    // convs
    conv1_kernel<<<dim3(B_ * T_ / 8), dim3(256), 0, stream>>>(x, W1, bc1, a1b);
    conv2_mfma<<<dim3(B_ * T_ / 64), dim3(256), 0, stream>>>(a1b, W2Tb, bc2, a2b);
    conv3_mfma<<<dim3(B_ * T_ / 32), dim3(256), 0, stream>>>(a2b, W3Tb, bc3, a3b);

    // X1 = a3 @ Wx1 + b1 (fp32 out)
    gemm_mfma<<<dim3(512, 1, 1), dim3(512), 0, stream>>>(a3b, WxT1b, b1, bufA, 128, 128);
    lstm_mfma<<<dim3(64), dim3(512), 0, stream>>>(bufA, WhT1b, nullptr, nullptr, out1b, cfb, 1);
    // X2 = out1 @ Wx2 + b2
    gemm_mfma<<<dim3(512, 1, 1), dim3(512), 0, stream>>>(out1b, WxT2b, b2, bufA, 128, 128);
    lstm_mfma<<<dim3(64), dim3(512), 0, stream>>>(bufA, WhT2b, cfb, out1b, out2b, cfb, 0);

    // Wd1 transpose into bufD (out1 dead; stream serial)
    twd_kernel<<<dim3(512, 8), dim3(256), 0, stream>>>(Wd1, WdTb);
    // dense: [256, 32768] @ WdT, split-K 64 x 512 -> partials in bufA
    gemm_mfma<<<dim3(2, 1, 64), dim3(512), 0, stream>>>(out2b, WdTb, nullptr, bufA, 32768, 512);
    reduce_kernel<<<dim3(512), dim3(256), 0, stream>>>(bufA, bd1, bufd);

    bn_kernel<<<dim3(16), dim3(256), 0, stream>>>(bufd, bns, bnb);
    head_kernel<<<dim3(256), dim3(64), 0, stream>>>(bufd, Wd2, bd2, outp);
}

// Round 5
// 757.348 us; speedup vs baseline: 4.3467x; 1.4490x over previous
//
#include <hip/hip_runtime.h>
#include <hip/hip_bf16.h>
#include <math.h>

#define B_ 256
#define T_ 256
#define HLS 128

typedef __bf16 bf16x8 __attribute__((ext_vector_type(8)));
typedef float f32x4 __attribute__((ext_vector_type(4)));
typedef unsigned int u32x4 __attribute__((ext_vector_type(4)));

__device__ __forceinline__ float leakyf(float v) { return v > 0.f ? v : 0.01f * v; }
__device__ __forceinline__ float sigfast(float x) { return __builtin_amdgcn_rcpf(1.f + __expf(-x)); }
__device__ __forceinline__ float tanhfast(float x) {
    float e = __expf(2.f * x);
    return 1.f - 2.f * __builtin_amdgcn_rcpf(e + 1.f);
}
__device__ __forceinline__ unsigned short bf16bits(float v) {
    union { __hip_bfloat16 h; unsigned short u; } cv;
    cv.h = __float2bfloat16(v);
    return cv.u;
}

// ---------------------------------------------------------------- conv1: [B,T,8] -> [B,T,32] bf16
__global__ __launch_bounds__(256) void conv1_kernel(
    const float* __restrict__ x, const float* __restrict__ W,
    const float* __restrict__ bias, __hip_bfloat16* __restrict__ out)
{
    int tid  = threadIdx.x;
    int co   = tid & 31;
    int tsub = tid >> 5;
    int b    = blockIdx.x >> 5;
    int t    = ((blockIdx.x & 31) << 3) + tsub;
    float acc = bias[co];
    #pragma unroll
    for (int k = 0; k < 5; ++k) {
        int tt = t + k - 2;
        if (tt < 0 || tt >= T_) continue;
        const float* xr = x + ((size_t)b * T_ + tt) * 8;
        #pragma unroll
        for (int ci = 0; ci < 8; ++ci)
            acc += xr[ci] * W[(k * 8 + ci) * 32 + co];
    }
    out[((size_t)b * T_ + t) * 32 + co] = __float2bfloat16(leakyf(acc));
}

// ---------------------------------------------------------------- weight preps
// 4x: [128][512] fp32 -> [512][128] bf16 (Wh1, Wh2, Wx1, Wx2)
__global__ __launch_bounds__(256) void prep_T128x4(
    const float* __restrict__ i0, const float* __restrict__ i1,
    const float* __restrict__ i2, const float* __restrict__ i3,
    __hip_bfloat16* __restrict__ o0, __hip_bfloat16* __restrict__ o1,
    __hip_bfloat16* __restrict__ o2, __hip_bfloat16* __restrict__ o3)
{
    int which = blockIdx.x >> 8;
    int idx = (blockIdx.x & 255) * 256 + threadIdx.x;   // 0..65535
    int k = idx >> 9, n = idx & 511;
    const float* in = which == 0 ? i0 : which == 1 ? i1 : which == 2 ? i2 : i3;
    __hip_bfloat16* out = which == 0 ? o0 : which == 1 ? o1 : which == 2 ? o2 : o3;
    out[n * 128 + k] = __float2bfloat16(in[idx]);
}
// W2[5][32][512] fp32 -> W2T[512][160] bf16
__global__ __launch_bounds__(256) void prep_w2T(const float* __restrict__ in, __hip_bfloat16* __restrict__ out)
{
    int idx = blockIdx.x * 256 + threadIdx.x;     // 0..81919
    int n = idx & 511, r = idx >> 9;
    int ci = r & 31, kt = r >> 5;
    out[n * 160 + kt * 32 + ci] = __float2bfloat16(in[idx]);
}
// W3[5,512,128] fp32 -> W3T[5,128,512] bf16
__global__ __launch_bounds__(256) void prep_w3t(const float* __restrict__ W3, __hip_bfloat16* __restrict__ W3T)
{
    int idx = blockIdx.x * 256 + threadIdx.x;     // 0..327679
    int co = idx & 127, rest = idx >> 7;
    int ci = rest & 511, k = rest >> 9;
    W3T[((size_t)(k * 128 + co)) * 512 + ci] = __float2bfloat16(W3[idx]);
}
// Wd1[32768,512] fp32 -> WdT[512][32768] bf16 via LDS tile transpose
__global__ __launch_bounds__(256) void twd_kernel(const float* __restrict__ Wd1, __hip_bfloat16* __restrict__ WdT)
{
    __shared__ float tile[64][65];
    int tid = threadIdx.x;
    int k0 = blockIdx.x * 64, n0 = blockIdx.y * 64;
    for (int i = tid; i < 4096; i += 256) {
        int k = i >> 6, n = i & 63;
        tile[k][n] = Wd1[(size_t)(k0 + k) * 512 + n0 + n];
    }
    __syncthreads();
    for (int i = tid; i < 4096; i += 256) {
        int n = i >> 6, k = i & 63;
        WdT[(size_t)(n0 + n) * 32768 + k0 + k] = __float2bfloat16(tile[k][n]);
    }
}

// ---------------------------------------------------------------- FUSED conv2+conv3: [B,T,32]bf16 -> [B,T,128]bf16
// Block: 128 t-rows, 512 threads (8 waves). a2 never touches HBM.
// For each ci-chunk (128 of conv2's 512 outputs): conv2-MFMA -> a2 LDS tile -> conv3-MFMA partial accumulate.
__global__ __launch_bounds__(512) void conv23_fused(
    const __hip_bfloat16* __restrict__ a1,   // [B*T][32]
    const __hip_bfloat16* __restrict__ W2T,  // [512][160]
    const float* __restrict__ bias2,
    const __hip_bfloat16* __restrict__ W3T,  // [5][128][512]
    const float* __restrict__ bias3,
    __hip_bfloat16* __restrict__ out)        // [B,T,128]
{
    __shared__ __align__(16) unsigned short a1t[148 * 40];   // rows t0-4..t0+143, pad 40
    __shared__ __align__(16) unsigned short a2t[132 * 136];  // rows t0-2..t0+129, pad 136, chunk-swizzled
    const int tid = threadIdx.x, l = tid & 63, w = tid >> 6;
    const int lr = l & 15, lg = l >> 4;
    const int b  = blockIdx.x >> 1;
    const int t0 = (blockIdx.x & 1) << 7;
    const size_t bT = (size_t)b * T_;

    // ---- stage a1 tile (coalesced 16B chunks, zero-padded at batch edges)
    for (int i = tid; i < 148 * 4; i += 512) {
        int row = i >> 2, c = i & 3;
        int t = t0 - 4 + row;
        u32x4 v = {0u, 0u, 0u, 0u};
        if (t >= 0 && t < T_) v = *(const u32x4*)&a1[(bT + t) * 32 + c * 8];
        *(u32x4*)&a1t[row * 40 + c * 8] = v;
    }

    f32x4 acc3[4][2];
    #pragma unroll
    for (int fm = 0; fm < 4; ++fm)
        #pragma unroll
        for (int n = 0; n < 2; ++n) acc3[fm][n] = (f32x4){0.f, 0.f, 0.f, 0.f};

    const int tq = w >> 2, cq = w & 3;   // conv3 wave tile: t-rows tq*64, co cq*32
    __syncthreads();

    #pragma unroll 1
    for (int cic = 0; cic < 4; ++cic) {
        // ---- conv2: wave w computes co columns cic*128 + w*16 + lr, all 132 needed rows
        {
            const int co2 = cic * 128 + w * 16 + lr;
            bf16x8 bf2[5];
            #pragma unroll
            for (int kt = 0; kt < 5; ++kt)
                bf2[kt] = *(const bf16x8*)&W2T[(size_t)co2 * 160 + kt * 32 + lg * 8];
            const float bb2 = bias2[co2];
            const int colc = w * 16 + lr;            // local a2 col
            const int chunkBase = colc >> 3, cLow = colc & 7;
            #pragma unroll 1
            for (int m = 0; m < 9; ++m) {
                f32x4 a = (f32x4){0.f, 0.f, 0.f, 0.f};
                #pragma unroll
                for (int kt = 0; kt < 5; ++kt) {
                    bf16x8 af = *(const bf16x8*)&a1t[(m * 16 + lr + kt) * 40 + lg * 8];
                    a = __builtin_amdgcn_mfma_f32_16x16x32_bf16(af, bf2[kt], a, 0, 0, 0);
                }
                #pragma unroll
                for (int r = 0; r < 4; ++r) {
                    int L = m * 16 + lg * 4 + r;
                    int t = t0 - 2 + L;
                    unsigned short v = 0;
                    if (t >= 0 && t < T_) v = bf16bits(leakyf(a[r] + bb2));
                    if (L < 132)
                        a2t[L * 136 + ((chunkBase ^ (L & 7)) << 3) + cLow] = v;
                }
            }
        }
        __syncthreads();
        // ---- conv3 partial accumulate over this ci chunk
        #pragma unroll 1
        for (int k = 0; k < 5; ++k) {
            const int rsw = (lr + k) & 7;   // swizzle key: L&7 == (lr+k)&7 for all read rows
            #pragma unroll
            for (int cf = 0; cf < 4; ++cf) {
                bf16x8 af3[4];
                #pragma unroll
                for (int fm = 0; fm < 4; ++fm) {
                    int L = tq * 64 + fm * 16 + lr + k;
                    af3[fm] = *(const bf16x8*)&a2t[L * 136 + (((cf * 4 + lg) ^ rsw) << 3)];
                }
                #pragma unroll
                for (int n = 0; n < 2; ++n) {
                    bf16x8 bf = *(const bf16x8*)&W3T[(size_t)(k * 128 + cq * 32 + n * 16 + lr) * 512
                                                     + cic * 128 + cf * 32 + lg * 8];
                    acc3[0][n] = __builtin_amdgcn_mfma_f32_16x16x32_bf16(af3[0], bf, acc3[0][n], 0, 0, 0);
                    acc3[1][n] = __builtin_amdgcn_mfma_f32_16x16x32_bf16(af3[1], bf, acc3[1][n], 0, 0, 0);
                    acc3[2][n] = __builtin_amdgcn_mfma_f32_16x16x32_bf16(af3[2], bf, acc3[2][n], 0, 0, 0);
                    acc3[3][n] = __builtin_amdgcn_mfma_f32_16x16x32_bf16(af3[3], bf, acc3[3][n], 0, 0, 0);
                }
            }
        }
        __syncthreads();
    }
    // ---- epilogue: bias + leaky, write a3 bf16
    #pragma unroll
    for (int n = 0; n < 2; ++n) {
        int co = cq * 32 + n * 16 + lr;
        float bb = bias3[co];
        #pragma unroll
        for (int fm = 0; fm < 4; ++fm) {
            #pragma unroll
            for (int r = 0; r < 4; ++r) {
                int t = t0 + tq * 64 + fm * 16 + lg * 4 + r;
                out[(bT + t) * 128 + co] = __float2bfloat16(leakyf(acc3[fm][n][r] + bb));
            }
        }
    }
}

// ---------------------------------------------------------------- unified bf16 MFMA GEMM: C[M,512] = A[M,K] @ BT[512,K]^T (+bias)
__global__ __launch_bounds__(512) void gemm_mfma(
    const __hip_bfloat16* __restrict__ A,
    const __hip_bfloat16* __restrict__ BT,
    const float* __restrict__ bias,
    float* __restrict__ C,
    int K, int klen)
{
    const int tid = threadIdx.x, l = tid & 63, w = tid >> 6;
    const int lr = l & 15, lg = l >> 4;
    const size_t m0 = (size_t)blockIdx.x * 128 + w * 16;
    const int k0 = blockIdx.z * klen;
    C += (size_t)blockIdx.z * gridDim.x * 128 * 512;

    f32x4 acc[32];
    #pragma unroll
    for (int q = 0; q < 32; ++q) acc[q] = (f32x4){0.f, 0.f, 0.f, 0.f};

    const __hip_bfloat16* Arow  = A + (m0 + lr) * (size_t)K + k0 + lg * 8;
    const __hip_bfloat16* Bbase = BT + (size_t)lr * K + k0 + lg * 8;

    const int nkf = klen >> 5;
    for (int kf = 0; kf < nkf; ++kf) {
        bf16x8 af = *(const bf16x8*)(Arow + kf * 32);
        #pragma unroll
        for (int q = 0; q < 32; ++q) {
            bf16x8 bf = *(const bf16x8*)(Bbase + (size_t)q * 16 * K + kf * 32);
            acc[q] = __builtin_amdgcn_mfma_f32_16x16x32_bf16(af, bf, acc[q], 0, 0, 0);
        }
    }
    #pragma unroll
    for (int q = 0; q < 32; ++q) {
        int n = q * 16 + lr;
        float bb = bias ? bias[n] : 0.f;
        #pragma unroll
        for (int r = 0; r < 4; ++r) {
            size_t m = m0 + lg * 4 + r;
            C[m * 512 + n] = acc[q][r] + bb;
        }
    }
}

// ---------------------------------------------------------------- LSTM via MFMA, in-register gates, 1 barrier/step
// 4 batch rows/block at A-rows {0,4,8,12}; lane (wave g, lr, lg) owns (batch row lg, col g*16+lr)
__global__ __launch_bounds__(512) void lstm_mfma(
    const float* __restrict__ X,             // [B,T,512] fp32 (x@Wx+b)
    const __hip_bfloat16* __restrict__ WhT,  // [512][128] bf16
    const float* __restrict__ cin,           // [B,128] or null
    const __hip_bfloat16* __restrict__ hin,  // prev layer out [B,T,128] (t=T-1) or null
    __hip_bfloat16* __restrict__ out,        // [B,T,128] bf16
    float* __restrict__ cf, int initZero)
{
    __shared__ __align__(16) __hip_bfloat16 lh[2][16 * 128];  // double-buffered h matrix
    const int tid = threadIdx.x, l = tid & 63, g = tid >> 6;  // wave 0..7
    const int lr = l & 15, lg = l >> 4;
    const int b0 = blockIdx.x * 4;
    const int j0 = g * 16 + lr;     // gate column 0..127
    const int hrow = lg * 4;        // A-row for this lane's batch row

    // preload Wh fragments: wave g owns gate tiles n = q*128 + g*16
    bf16x8 wb[4][4];
    #pragma unroll
    for (int q = 0; q < 4; ++q)
        #pragma unroll
        for (int kf = 0; kf < 4; ++kf)
            wb[q][kf] = *(const bf16x8*)&WhT[(size_t)(q * 128 + g * 16 + lr) * 128 + kf * 32 + lg * 8];

    // zero both h buffers
    for (int i = tid; i < 2 * 2048; i += 512) ((__hip_bfloat16*)lh)[i] = __float2bfloat16(0.f);
    __syncthreads();

    float c;
    {
        __hip_bfloat16 h0;
        if (initZero) { c = 0.f; h0 = __float2bfloat16(0.f); }
        else {
            c  = cin[(size_t)(b0 + lg) * 128 + j0];
            h0 = hin[((size_t)(b0 + lg) * T_ + (T_ - 1)) * 128 + j0];
        }
        lh[0][hrow * 128 + ((((j0 >> 3) ^ (hrow & 7)) << 3) | (j0 & 7))] = h0;
    }
    __syncthreads();

    const float* Xl = X + ((size_t)(b0 + lg) * T_) * 512 + j0;
    float xc0 = Xl[0], xc1 = Xl[128], xc2 = Xl[256], xc3 = Xl[384];

    for (int t = 0; t < T_; ++t) {
        float xn0 = 0.f, xn1 = 0.f, xn2 = 0.f, xn3 = 0.f;
        if (t < T_ - 1) {
            const float* Xp = Xl + (size_t)(t + 1) * 512;
            xn0 = Xp[0]; xn1 = Xp[128]; xn2 = Xp[256]; xn3 = Xp[384];
        }
        const int cur = t & 1;
        bf16x8 af[4];
        #pragma unroll
        for (int kf = 0; kf < 4; ++kf) {
            int chunk = (kf * 4 + lg) ^ (lr & 7);
            af[kf] = *(const bf16x8*)&lh[cur][lr * 128 + chunk * 8];
        }
        f32x4 a0 = {0.f,0.f,0.f,0.f}, a1 = {0.f,0.f,0.f,0.f}, a2 = {0.f,0.f,0.f,0.f}, a3 = {0.f,0.f,0.f,0.f};
        #pragma unroll
        for (int kf = 0; kf < 4; ++kf) {
            a0 = __builtin_amdgcn_mfma_f32_16x16x32_bf16(af[kf], wb[0][kf], a0, 0, 0, 0);
            a1 = __builtin_amdgcn_mfma_f32_16x16x32_bf16(af[kf], wb[1][kf], a1, 0, 0, 0);
            a2 = __builtin_amdgcn_mfma_f32_16x16x32_bf16(af[kf], wb[2][kf], a2, 0, 0, 0);
            a3 = __builtin_amdgcn_mfma_f32_16x16x32_bf16(af[kf], wb[3][kf], a3, 0, 0, 0);
        }
        // lane (lr,lg) reg 0 = C[row hrow][col lr] = z[batch lg][gate q][j0]
        float zi = a0[0] + xc0;
        float zf = a1[0] + xc1;
        float zg = a2[0] + xc2;
        float zo = a3[0] + xc3;
        float ig = sigfast(zi), fg = sigfast(zf);
        float gg = tanhfast(zg), og = sigfast(zo);
        c = fg * c + ig * gg;
        float h = og * tanhfast(c);
        __hip_bfloat16 hb = __float2bfloat16(h);
        lh[cur ^ 1][hrow * 128 + ((((j0 >> 3) ^ (hrow & 7)) << 3) | (j0 & 7))] = hb;
        out[((size_t)(b0 + lg) * T_ + t) * 128 + j0] = hb;
        __syncthreads();
        xc0 = xn0; xc1 = xn1; xc2 = xn2; xc3 = xn3;
    }
    cf[(size_t)(b0 + lg) * 128 + j0] = c;
}

// ---------------------------------------------------------------- split-K reduce (64 partials) + bias
__global__ __launch_bounds__(256) void reduce_kernel(
    const float* __restrict__ part, const float* __restrict__ bias,
    float* __restrict__ d)
{
    int i = blockIdx.x * 256 + threadIdx.x;   // 0..131071
    float s = bias[i & 511];
    #pragma unroll
    for (int p = 0; p < 64; ++p) s += part[(size_t)p * 131072 + i];
    d[i] = s;
}

// ---------------------------------------------------------------- BatchNorm (batch stats) + leaky, row-parallel
__global__ __launch_bounds__(256) void bn_kernel(
    float* __restrict__ d, const float* __restrict__ scale, const float* __restrict__ bias)
{
    __shared__ float ss[8][32], ss2[8][32];
    int tid = threadIdx.x;
    int cc = tid & 31, rg = tid >> 5;
    int col = blockIdx.x * 32 + cc;
    float s = 0.f, s2 = 0.f;
    for (int r = rg * 32; r < rg * 32 + 32; ++r) {
        float v = d[(size_t)r * 512 + col];
        s += v; s2 += v * v;
    }
    ss[rg][cc] = s; ss2[rg][cc] = s2;
    __syncthreads();
    float st = 0.f, s2t = 0.f;
    #pragma unroll
    for (int i = 0; i < 8; ++i) { st += ss[i][cc]; s2t += ss2[i][cc]; }
    float mean = st * (1.f / 256.f);
    float var  = s2t * (1.f / 256.f) - mean * mean;
    float inv  = rsqrtf(var + 1e-5f);
    float sc = scale[col] * inv;
    float bi = bias[col] - mean * sc;
    for (int r = rg * 32; r < rg * 32 + 32; ++r) {
        float v = d[(size_t)r * 512 + col] * sc + bi;
        d[(size_t)r * 512 + col] = leakyf(v);
    }
}

// ---------------------------------------------------------------- head GEMV + softmax
__global__ __launch_bounds__(64) void head_kernel(
    const float* __restrict__ d, const float* __restrict__ Wd2,
    const float* __restrict__ bd2, float* __restrict__ out)
{
    int r = blockIdx.x, l = threadIdx.x;
    float acc[10] = {};
    for (int k = l; k < 512; k += 64) {
        float v = d[(size_t)r * 512 + k];
        #pragma unroll
        for (int n = 0; n < 10; ++n) acc[n] += v * Wd2[k * 10 + n];
    }
    #pragma unroll
    for (int n = 0; n < 10; ++n)
        for (int off = 32; off; off >>= 1) acc[n] += __shfl_down(acc[n], off);
    if (l == 0) {
        float mx = -1e30f;
        #pragma unroll
        for (int n = 0; n < 10; ++n) { acc[n] += bd2[n]; mx = fmaxf(mx, acc[n]); }
        float s = 0.f;
        #pragma unroll
        for (int n = 0; n < 10; ++n) { acc[n] = expf(acc[n] - mx); s += acc[n]; }
        float invs = 1.f / s;
        #pragma unroll
        for (int n = 0; n < 10; ++n) out[(size_t)r * 10 + n] = acc[n] * invs;
    }
}

// ----------------------------------------------------------------
extern "C" void kernel_launch(void* const* d_in, const int* in_sizes, int n_in,
                              void* d_out, int out_size, void* d_ws, size_t ws_size,
                              hipStream_t stream)
{
    const float* x   = (const float*)d_in[0];
    const float* W1  = (const float*)d_in[1];
    const float* bc1 = (const float*)d_in[2];
    const float* W2  = (const float*)d_in[3];
    const float* bc2 = (const float*)d_in[4];
    const float* W3  = (const float*)d_in[5];
    const float* bc3 = (const float*)d_in[6];
    const float* Wx1 = (const float*)d_in[7];
    const float* Wh1 = (const float*)d_in[8];
    const float* b1  = (const float*)d_in[9];
    const float* Wx2 = (const float*)d_in[10];
    const float* Wh2 = (const float*)d_in[11];
    const float* b2  = (const float*)d_in[12];
    const float* Wd1 = (const float*)d_in[13];
    const float* bd1 = (const float*)d_in[14];
    const float* bns = (const float*)d_in[15];
    const float* bnb = (const float*)d_in[16];
    const float* Wd2 = (const float*)d_in[17];
    const float* bd2 = (const float*)d_in[18];
    float* outp = (float*)d_out;

    const size_t BT = (size_t)B_ * T_;
    float* ws   = (float*)d_ws;
    float* bufA = ws;                         // BT*512 f: a1(bf16, tail) -> X1 -> X2 -> dense partials
    float* bufC = bufA + BT * 512;            // BT*128 f: a3(bf16) -> out2(bf16)
    float* bufD = bufC + BT * 128;            // BT*128 f: out1(bf16) -> WdT(bf16)
    float* bufd = bufD + BT * 128;            // 131072 f
    float* cfb  = bufd + 131072;              // 32768 f
    __hip_bfloat16* WhT1b = (__hip_bfloat16*)(cfb + 32768);
    __hip_bfloat16* WhT2b = WhT1b + 65536;
    __hip_bfloat16* WxT1b = WhT2b + 65536;
    __hip_bfloat16* WxT2b = WxT1b + 65536;
    __hip_bfloat16* W2Tb  = WxT2b + 65536;    // 81920 bf16
    __hip_bfloat16* W3Tb  = W2Tb + 81920;     // 327680 bf16

    __hip_bfloat16* a1b   = (__hip_bfloat16*)(bufA + BT * 256);  // tail of bufA
    __hip_bfloat16* a3b   = (__hip_bfloat16*)bufC;
    __hip_bfloat16* out1b = (__hip_bfloat16*)bufD;
    __hip_bfloat16* out2b = (__hip_bfloat16*)bufC;
    __hip_bfloat16* WdTb  = (__hip_bfloat16*)bufD;

    // weight preps
    prep_T128x4<<<dim3(1024), dim3(256), 0, stream>>>(Wh1, Wh2, Wx1, Wx2, WhT1b, WhT2b, WxT1b, WxT2b);
    prep_w2T<<<dim3(320), dim3(256), 0, stream>>>(W2, W2Tb);
    prep_w3t<<<dim3(1280), dim3(256), 0, stream>>>(W3, W3Tb);

    // convs: conv1 scalar, conv2+conv3 fused MFMA (a2 stays in LDS)
    conv1_kernel<<<dim3(B_ * T_ / 8), dim3(256), 0, stream>>>(x, W1, bc1, a1b);
    conv23_fused<<<dim3(B_ * T_ / 128), dim3(512), 0, stream>>>(a1b, W2Tb, bc2, W3Tb, bc3, a3b);

    // X1 = a3 @ Wx1 + b1 (fp32 out)  [clobbers a1b region: a1 is dead]
    gemm_mfma<<<dim3(512, 1, 1), dim3(512), 0, stream>>>(a3b, WxT1b, b1, bufA, 128, 128);
    lstm_mfma<<<dim3(64), dim3(512), 0, stream>>>(bufA, WhT1b, nullptr, nullptr, out1b, cfb, 1);
    // X2 = out1 @ Wx2 + b2
    gemm_mfma<<<dim3(512, 1, 1), dim3(512), 0, stream>>>(out1b, WxT2b, b2, bufA, 128, 128);
    lstm_mfma<<<dim3(64), dim3(512), 0, stream>>>(bufA, WhT2b, cfb, out1b, out2b, cfb, 0);

    // Wd1 transpose into bufD (out1 dead; stream serial)
    twd_kernel<<<dim3(512, 8), dim3(256), 0, stream>>>(Wd1, WdTb);
    // dense: [256, 32768] @ WdT, split-K 64 x 512 -> partials in bufA
    gemm_mfma<<<dim3(2, 1, 64), dim3(512), 0, stream>>>(out2b, WdTb, nullptr, bufA, 32768, 512);
    reduce_kernel<<<dim3(512), dim3(256), 0, stream>>>(bufA, bd1, bufd);

    bn_kernel<<<dim3(16), dim3(256), 0, stream>>>(bufd, bns, bnb);
    head_kernel<<<dim3(256), dim3(64), 0, stream>>>(bufd, Wd2, bd2, outp);
}